// Round 4
// baseline (829.164 us; speedup 1.0000x reference)
//
#include <hip/hip_runtime.h>
#include <math.h>

#define NN 100000
#define SCALE 0.8408964152537145f  // inv_sqrt_tau(=2) * 32^-0.25
#define HALF_SCALE2 0.3535533905932738f // 0.5 * SCALE^2
#define RATIO 0.125f               // 64^-0.5
#define KEPS 1e-6f

// ws layout (float offsets)
#define WS_KMAX 0
#define WS_KVSKS 8          // 16384 kvs fp32 + 512 ks fp32
#define WS_KVST 16904       // kvsT bf16 [8][32][64] -> 8192 floats
#define WS_W2Q 25096        // fp32 [128][512]
#define WS_W2K 90632        // fp32 [128][512]
#define WS_B2Q 156168       // 512
#define WS_B2K 156680       // 512
#define WS_W2QT 157192      // bf16 [512][128] -> 32768 floats
#define WS_W2KT 189960      // bf16 [512][128]
#define WS_WQST 222728      // bf16 [256][128] (SCALE*Wq)^T -> 16384 floats
#define WS_WOT 239112       // bf16 [128][256] Wo^T -> 16384 floats
#define WS_BQS 255496       // 256 fp32 (SCALE*Wq_b)
#define WS_WKVT 255752      // bf16 [512][128] [Wk|Wv]^T -> 32768 floats
#define WS_BKV 288520       // 512 fp32 [bk|bv]
#define WS_PART 289032      // nb * 16896

typedef __attribute__((ext_vector_type(8))) short short8;
typedef __attribute__((ext_vector_type(4))) float f32x4;

#define MFMA16(a, b, c) __builtin_amdgcn_mfma_f32_16x16x32_bf16((a), (b), (c), 0, 0, 0)

__device__ __forceinline__ short f2bf(float f) {
    union { float f; unsigned u; } a; a.f = f;
    unsigned r = a.u + 0x7fffu + ((a.u >> 16) & 1u);
    return (short)(r >> 16);
}
__device__ __forceinline__ float bf2f(short s) {
    union { float f; unsigned u; } a; a.u = ((unsigned)(unsigned short)s) << 16;
    return a.f;
}

__device__ __forceinline__ float bsum16(float v) {
    v += __shfl_xor(v, 1); v += __shfl_xor(v, 2);
    v += __shfl_xor(v, 4); v += __shfl_xor(v, 8);
    return v;
}
__device__ __forceinline__ float bmax16(float v) {
    v = fmaxf(v, __shfl_xor(v, 1)); v = fmaxf(v, __shfl_xor(v, 2));
    v = fmaxf(v, __shfl_xor(v, 4)); v = fmaxf(v, __shfl_xor(v, 8));
    return v;
}

__device__ __forceinline__ void atomicMaxFloat(float* addr, float val) {
    int* ai = (int*)addr;
    int cur = *((volatile int*)ai);
    while (val > __int_as_float(cur)) {
        int assumed = cur;
        cur = atomicCAS(ai, assumed, __float_as_int(val));
        if (cur == assumed) break;
    }
}

// ---------- fold: W2[j, h*64+m] = SCALE * sum_d W[j, h*32+d]*proj[m,d] ----------
__global__ __launch_bounds__(256) void fold_kernel(
    const float* __restrict__ W, const float* __restrict__ b,
    const float* __restrict__ proj,
    float* __restrict__ W2, float* __restrict__ b2)
{
    const int idx = blockIdx.x * 256 + threadIdx.x;
    if (idx >= 129 * 512) return;
    const int row = idx >> 9;
    const int col = idx & 511;
    const int h = col >> 6, m = col & 63;
    const float* src = (row < 128) ? (W + row * 256 + h * 32) : (b + h * 32);
    float s = 0.f;
#pragma unroll
    for (int d = 0; d < 32; ++d) s = fmaf(src[d], proj[m * 32 + d], s);
    s *= SCALE;
    if (row < 128) W2[row * 512 + col] = s;
    else           b2[col] = s;
}

// ---------- prep: bf16 transposed weights ----------
__global__ __launch_bounds__(256) void prep_kernel(
    const float* __restrict__ Wq_w, const float* __restrict__ Wq_b,
    const float* __restrict__ Wk_w, const float* __restrict__ Wk_b,
    const float* __restrict__ Wv_w, const float* __restrict__ Wv_b,
    const float* __restrict__ Wo_w, float* __restrict__ ws)
{
    int idx = blockIdx.x * 256 + threadIdx.x;
    if (idx < 32768) {  // WqsT [256][128]
        int c = idx >> 7, k = idx & 127;
        ((short*)(ws + WS_WQST))[idx] = f2bf(SCALE * Wq_w[k * 256 + c]);
        return;
    }
    idx -= 32768;
    if (idx < 65536) {  // W2qT [512][128]
        int c = idx >> 7, k = idx & 127;
        ((short*)(ws + WS_W2QT))[idx] = f2bf(ws[WS_W2Q + k * 512 + c]);
        return;
    }
    idx -= 65536;
    if (idx < 65536) {  // W2kT [512][128]
        int c = idx >> 7, k = idx & 127;
        ((short*)(ws + WS_W2KT))[idx] = f2bf(ws[WS_W2K + k * 512 + c]);
        return;
    }
    idx -= 65536;
    if (idx < 32768) {  // WoT [128][256]
        int o = idx >> 8, c = idx & 255;
        ((short*)(ws + WS_WOT))[idx] = f2bf(Wo_w[c * 128 + o]);
        return;
    }
    idx -= 32768;
    if (idx < 256) { ws[WS_BQS + idx] = SCALE * Wq_b[idx]; return; }
    idx -= 256;
    if (idx < 65536) {  // WkvT [512][128]: rows 0-255 k cols, 256-511 v cols
        int c = idx >> 7, k = idx & 127;
        ((short*)(ws + WS_WKVT))[idx] =
            f2bf(c < 256 ? Wk_w[k * 256 + c] : Wv_w[k * 256 + (c - 256)]);
        return;
    }
    idx -= 65536;
    if (idx < 512) ws[WS_BKV + idx] = (idx < 256) ? Wk_b[idx] : Wv_b[idx - 256];
}

__global__ void init_kernel(float* kmax) {
    if (threadIdx.x < 8) kmax[threadIdx.x] = -1e30f;
}

// ---------- kmax via MFMA: global per-head max of kdash (one 64-row tile/block) ----------
__global__ __launch_bounds__(256) void kmax_mfma_kernel(
    const float* __restrict__ x, const float* __restrict__ ws, float* __restrict__ kmax)
{
    __shared__ char smem[16384];   // x tile [64][128] bf16, swizzled
    const short* w2kt = (const short*)(ws + WS_W2KT);
    const float* b2k = ws + WS_B2K;
    const int t = threadIdx.x, w = t >> 6, l = t & 63, lg = l >> 4, li = l & 15;
    float b2r[8];
#pragma unroll
    for (int nc = 0; nc < 8; ++nc) b2r[nc] = b2k[w * 128 + nc * 16 + li];
    float mx0 = -1e30f, mx1 = -1e30f;

    const int n0 = blockIdx.x * 64;
    {
        const int sr = t >> 2, sp = t & 3;
        float f[32];
        if (n0 + sr < NN) {
            const float* gp = x + (size_t)(n0 + sr) * 128 + sp * 32;
#pragma unroll
            for (int i = 0; i < 8; ++i) {
                float4 v = *(const float4*)(gp + i * 4);
                f[i * 4] = v.x; f[i * 4 + 1] = v.y; f[i * 4 + 2] = v.z; f[i * 4 + 3] = v.w;
            }
        } else {
#pragma unroll
            for (int i = 0; i < 32; ++i) f[i] = 0.f;
        }
        const int rb = sr * 256, sw = (sr & 7) << 4;
#pragma unroll
        for (int j = 0; j < 4; ++j) {
            short8 s;
#pragma unroll
            for (int e = 0; e < 8; ++e) s[e] = f2bf(f[j * 8 + e]);
            *(short8*)(smem + rb + ((sp * 64 + 16 * j) ^ sw)) = s;
        }
    }
    __syncthreads();
#pragma unroll
    for (int hf = 0; hf < 2; ++hf) {
        f32x4 acc[4][4];
#pragma unroll
        for (int mr = 0; mr < 4; ++mr)
#pragma unroll
            for (int nc = 0; nc < 4; ++nc) acc[mr][nc] = (f32x4){0.f, 0.f, 0.f, 0.f};
#pragma unroll
        for (int kk = 0; kk < 4; ++kk) {
            short8 afr[4], bf[4];
#pragma unroll
            for (int mr = 0; mr < 4; ++mr) {
                const int row = mr * 16 + li;
                afr[mr] = *(const short8*)(smem + row * 256 + (((kk * 32 + lg * 8) * 2) ^ ((row & 7) << 4)));
            }
#pragma unroll
            for (int nc = 0; nc < 4; ++nc)
                bf[nc] = *(const short8*)&w2kt[(w * 128 + (hf * 4 + nc) * 16 + li) * 128 + kk * 32 + lg * 8];
#pragma unroll
            for (int mr = 0; mr < 4; ++mr)
#pragma unroll
                for (int nc = 0; nc < 4; ++nc) acc[mr][nc] = MFMA16(afr[mr], bf[nc], acc[mr][nc]);
        }
#pragma unroll
        for (int mr = 0; mr < 4; ++mr)
#pragma unroll
            for (int r = 0; r < 4; ++r) {
                const int row = mr * 16 + lg * 4 + r;
                if (n0 + row < NN) {
#pragma unroll
                    for (int nc = 0; nc < 4; ++nc) {
                        const float v = acc[mr][nc][r] + b2r[hf * 4 + nc];
                        if (hf == 0) mx0 = fmaxf(mx0, v); else mx1 = fmaxf(mx1, v);
                    }
                }
            }
    }
    mx0 = bmax16(mx0); mx0 = fmaxf(mx0, __shfl_xor(mx0, 16)); mx0 = fmaxf(mx0, __shfl_xor(mx0, 32));
    mx1 = bmax16(mx1); mx1 = fmaxf(mx1, __shfl_xor(mx1, 16)); mx1 = fmaxf(mx1, __shfl_xor(mx1, 32));
    if (l == 0) {
        atomicMaxFloat(&kmax[2 * w], mx0);
        atomicMaxFloat(&kmax[2 * w + 1], mx1);
    }
}

// ---------- kvs via MFMA ----------
// smem: [0,8192) xs [32][256B]; [8192,24576) kpT per-wave 4KB [64 m][64B];
//       [24576,40960) vT [256][64B]; [40960,41984) diag [32][8] f32
__global__ __launch_bounds__(256) void kvs_mfma_kernel(
    const float* __restrict__ x, const float* __restrict__ ws,
    float* __restrict__ partials, int nb)
{
    __shared__ char smem[41984];
    const short* wkvt = (const short*)(ws + WS_WKVT);
    const short* w2kt = (const short*)(ws + WS_W2KT);
    const float* bkv  = ws + WS_BKV;
    const float* b2k  = ws + WS_B2K;
    const float* kmax = ws + WS_KMAX;
    float* diagL = (float*)(smem + 40960);

    const int t = threadIdx.x, w = t >> 6, l = t & 63, lg = l >> 4, li = l & 15;
    float bkv_r[8], b2_r[8];
#pragma unroll
    for (int nc = 0; nc < 8; ++nc) {
        bkv_r[nc] = bkv[w * 128 + nc * 16 + li];
        b2_r[nc]  = b2k[w * 128 + nc * 16 + li];
    }
    const float km0 = kmax[2 * w], km1 = kmax[2 * w + 1];

    f32x4 ak[2][4][2];   // persistent kvs accumulators [hi][mr(m)][nc(d)]
#pragma unroll
    for (int hi = 0; hi < 2; ++hi)
#pragma unroll
        for (int mr = 0; mr < 4; ++mr)
#pragma unroll
            for (int nc = 0; nc < 2; ++nc) ak[hi][mr][nc] = (f32x4){0.f,0.f,0.f,0.f};
    float ksacc[8];
#pragma unroll
    for (int nc = 0; nc < 8; ++nc) ksacc[nc] = 0.f;

    for (int tile = blockIdx.x; tile < 3125; tile += nb) {
        const int n0 = tile * 32;
        __syncthreads();   // protect smem from previous tile's readers
        {
            const int sr = t >> 3, sp = t & 7;
            const float* gp = x + (size_t)(n0 + sr) * 128 + sp * 16;
            float f[16];
#pragma unroll
            for (int i = 0; i < 4; ++i) {
                float4 v = *(const float4*)(gp + i * 4);
                f[i*4] = v.x; f[i*4+1] = v.y; f[i*4+2] = v.z; f[i*4+3] = v.w;
            }
            const int rb = sr * 256, sw = (sr & 7) << 4;
#pragma unroll
            for (int j = 0; j < 2; ++j) {
                short8 s;
#pragma unroll
                for (int e = 0; e < 8; ++e) s[e] = f2bf(f[j * 8 + e]);
                *(short8*)(smem + rb + ((sp * 32 + 16 * j) ^ sw)) = s;
            }
        }
        __syncthreads();
        short8 af[2][4];
#pragma unroll
        for (int mr = 0; mr < 2; ++mr) {
            const int row = mr * 16 + li, rb = row * 256, sw = (row & 7) << 4;
#pragma unroll
            for (int kk = 0; kk < 4; ++kk)
                af[mr][kk] = *(const short8*)(smem + rb + (((kk * 32 + lg * 8) * 2) ^ sw));
        }
        // ---- GEMM1: [k|v] = x @ [Wk|Wv], split into nc halves ----
#pragma unroll
        for (int hf = 0; hf < 2; ++hf) {
            f32x4 acc[2][4];
#pragma unroll
            for (int mr = 0; mr < 2; ++mr)
#pragma unroll
                for (int nc = 0; nc < 4; ++nc) acc[mr][nc] = (f32x4){0.f,0.f,0.f,0.f};
#pragma unroll
            for (int kk = 0; kk < 4; ++kk) {
                short8 bb[4];
#pragma unroll
                for (int nc = 0; nc < 4; ++nc)
                    bb[nc] = *(const short8*)&wkvt[(w * 128 + (hf * 4 + nc) * 16 + li) * 128 + kk * 32 + lg * 8];
#pragma unroll
                for (int mr = 0; mr < 2; ++mr)
#pragma unroll
                    for (int nc = 0; nc < 4; ++nc) acc[mr][nc] = MFMA16(af[mr][kk], bb[nc], acc[mr][nc]);
            }
            if (w < 2) {
#pragma unroll
                for (int mr = 0; mr < 2; ++mr)
#pragma unroll
                    for (int r = 0; r < 4; ++r) {
                        const int n = mr * 16 + lg * 4 + r;
#pragma unroll
                        for (int jj = 0; jj < 2; ++jj) {
                            const float v0 = acc[mr][2*jj][r]   + bkv_r[hf*4 + 2*jj];
                            const float v1 = acc[mr][2*jj+1][r] + bkv_r[hf*4 + 2*jj+1];
                            const float s = bsum16(v0 * v0 + v1 * v1);
                            if (li == 0) diagL[n * 8 + w * 4 + hf * 2 + jj] = HALF_SCALE2 * s;
                        }
                    }
            } else {
#pragma unroll
                for (int mr = 0; mr < 2; ++mr)
#pragma unroll
                    for (int nc = 0; nc < 4; ++nc) {
                        short4 s4;
                        s4.x = f2bf(acc[mr][nc][0] + bkv_r[hf*4+nc]);
                        s4.y = f2bf(acc[mr][nc][1] + bkv_r[hf*4+nc]);
                        s4.z = f2bf(acc[mr][nc][2] + bkv_r[hf*4+nc]);
                        s4.w = f2bf(acc[mr][nc][3] + bkv_r[hf*4+nc]);
                        const int row = (w - 2) * 128 + (hf * 4 + nc) * 16 + li;
                        const int b = 32 * mr + 8 * lg;
                        *(short4*)(smem + 24576 + row * 64 +
                                   ((((b >> 4) ^ ((row >> 1) & 3)) << 4) | (b & 15))) = s4;
                    }
            }
        }
        __syncthreads();   // diag + vT visible
        // ---- per head: GEMM2 (kdash->kp->kpT) then GEMM3 (kvs += kpT @ v) ----
#pragma unroll
        for (int hf = 0; hf < 2; ++hf) {
            f32x4 acd[2][4];
#pragma unroll
            for (int mr = 0; mr < 2; ++mr)
#pragma unroll
                for (int nc = 0; nc < 4; ++nc) acd[mr][nc] = (f32x4){0.f,0.f,0.f,0.f};
#pragma unroll
            for (int kk = 0; kk < 4; ++kk) {
                short8 bb[4];
#pragma unroll
                for (int nc = 0; nc < 4; ++nc)
                    bb[nc] = *(const short8*)&w2kt[(w * 128 + (hf * 4 + nc) * 16 + li) * 128 + kk * 32 + lg * 8];
#pragma unroll
                for (int mr = 0; mr < 2; ++mr)
#pragma unroll
                    for (int nc = 0; nc < 4; ++nc) acd[mr][nc] = MFMA16(af[mr][kk], bb[nc], acd[mr][nc]);
            }
            const float km = hf ? km1 : km0;
            const int hh = 2 * w + hf;
#pragma unroll
            for (int mr = 0; mr < 2; ++mr)
#pragma unroll
                for (int nc = 0; nc < 4; ++nc) {
                    short4 s4;
#pragma unroll
                    for (int r = 0; r < 4; ++r) {
                        const int n = mr * 16 + lg * 4 + r;
                        const float val = acd[mr][nc][r] + b2_r[hf * 4 + nc];
                        const float kp = RATIO * (__expf(val - diagL[n * 8 + hh] - km) + KEPS);
                        const short sb = f2bf(kp);
                        ksacc[hf * 4 + nc] += bf2f(sb);
                        if (r == 0) s4.x = sb; else if (r == 1) s4.y = sb;
                        else if (r == 2) s4.z = sb; else s4.w = sb;
                    }
                    const int mrow = nc * 16 + li;
                    const int b = 32 * mr + 8 * lg;
                    *(short4*)(smem + 8192 + w * 4096 + mrow * 64 +
                               ((((b >> 4) ^ ((mrow >> 1) & 3)) << 4) | (b & 15))) = s4;
                }
            // GEMM3 for head hh (kpT is per-wave, same-wave in-order LDS)
            short8 aa[4], bv[2];
#pragma unroll
            for (int mr = 0; mr < 4; ++mr) {
                const int row = mr * 16 + li;
                aa[mr] = *(const short8*)(smem + 8192 + w * 4096 + row * 64 +
                                          ((lg ^ ((row >> 1) & 3)) << 4));
            }
#pragma unroll
            for (int nc = 0; nc < 2; ++nc) {
                const int vrow = hh * 32 + nc * 16 + li;
                bv[nc] = *(const short8*)(smem + 24576 + vrow * 64 +
                                          ((lg ^ ((vrow >> 1) & 3)) << 4));
            }
#pragma unroll
            for (int mr = 0; mr < 4; ++mr)
#pragma unroll
                for (int nc = 0; nc < 2; ++nc)
                    ak[hf][mr][nc] = MFMA16(aa[mr], bv[nc], ak[hf][mr][nc]);
        }
    }
    // ---- write per-block partials ----
    float* pb = partials + (size_t)blockIdx.x * 16896;
#pragma unroll
    for (int hi = 0; hi < 2; ++hi) {
        const int h = 2 * w + hi;
#pragma unroll
        for (int mr = 0; mr < 4; ++mr)
#pragma unroll
            for (int nc = 0; nc < 2; ++nc)
#pragma unroll
                for (int r = 0; r < 4; ++r) {
                    const int m = mr * 16 + lg * 4 + r;
                    const int d = nc * 16 + li;
                    pb[(h * 64 + m) * 32 + d] = ak[hi][mr][nc][r];
                }
    }
#pragma unroll
    for (int nc = 0; nc < 8; ++nc) {
        float s = ksacc[nc];
        s += __shfl_xor(s, 16); s += __shfl_xor(s, 32);
        if (lg == 0) {
            const int h = 2 * w + (nc >> 2);
            const int m = (nc & 3) * 16 + li;
            pb[16384 + h * 64 + m] = s;
        }
    }
}

__global__ __launch_bounds__(256) void reduce_kernel(
    const float* __restrict__ partials, float* __restrict__ ws, int nb)
{
    const int idx = blockIdx.x * 256 + threadIdx.x;
    if (idx >= 16896) return;
    float s = 0.f;
    for (int b = 0; b < nb; ++b) s += partials[(size_t)b * 16896 + idx];
    ws[WS_KVSKS + idx] = s;
    if (idx < 16384) {
        const int h = idx >> 11, m = (idx >> 5) & 63, d = idx & 31;
        ((short*)(ws + WS_KVST))[(h * 32 + d) * 64 + m] = f2bf(s);
    }
}

// ---------- fused MFMA output kernel (one 32-row tile per block) ----------
// smem: [0,16384) xs [32][256B] -> zs [32][512B]; [16384,32768) qp per-wave 4KB [16][256B]
__global__ __launch_bounds__(256) void out_mfma_kernel(
    const float* __restrict__ x, const float* __restrict__ ws,
    const float* __restrict__ alpha, const float* __restrict__ beta,
    const float* __restrict__ Wo_b, float* __restrict__ out)
{
    __shared__ char smem[32768];
    const short* wqst = (const short*)(ws + WS_WQST);
    const short* w2qt = (const short*)(ws + WS_W2QT);
    const short* wot  = (const short*)(ws + WS_WOT);
    const short* kvst = (const short*)(ws + WS_KVST);
    const float* bqs  = ws + WS_BQS;
    const float* b2q  = ws + WS_B2Q;
    const float* ksum = ws + WS_KVSKS + 16384;

    const int t = threadIdx.x, w = t >> 6, l = t & 63, lg = l >> 4, li = l & 15;
    const float a_ = __expf(alpha[0]), b_ = __expf(beta[0]);
    const float a2 = a_ * a_, bc = b_ * (a_ + 1.f);

    float bq_r[4], b2_r[8], ksv[8], bo_r[2];
#pragma unroll
    for (int nc = 0; nc < 4; ++nc) bq_r[nc] = bqs[w * 64 + nc * 16 + li];
#pragma unroll
    for (int nc = 0; nc < 8; ++nc) {
        const int c = w * 128 + nc * 16 + li;
        b2_r[nc] = b2q[c]; ksv[nc] = ksum[c];
    }
#pragma unroll
    for (int nc = 0; nc < 2; ++nc) bo_r[nc] = Wo_b[w * 32 + nc * 16 + li];

    const int n0 = blockIdx.x * 32;
    {
        const int sr = t >> 3, sp = t & 7;
        const float* gp = x + (size_t)(n0 + sr) * 128 + sp * 16;
        float f[16];
#pragma unroll
        for (int i = 0; i < 4; ++i) {
            float4 v = *(const float4*)(gp + i * 4);
            f[i*4] = v.x; f[i*4+1] = v.y; f[i*4+2] = v.z; f[i*4+3] = v.w;
        }
        const int rb = sr * 256, sw = (sr & 7) << 4;
#pragma unroll
        for (int j = 0; j < 2; ++j) {
            short8 s;
#pragma unroll
            for (int e = 0; e < 8; ++e) s[e] = f2bf(f[j * 8 + e]);
            *(short8*)(smem + rb + ((sp * 32 + 16 * j) ^ sw)) = s;
        }
    }
    __syncthreads();
    short8 af[2][4];
#pragma unroll
    for (int mr = 0; mr < 2; ++mr) {
        const int row = mr * 16 + li, rb = row * 256, sw = (row & 7) << 4;
#pragma unroll
        for (int kk = 0; kk < 4; ++kk)
            af[mr][kk] = *(const short8*)(smem + rb + (((kk * 32 + lg * 8) * 2) ^ sw));
    }
    __syncthreads();   // all waves have af; region A reusable as zs

#pragma unroll
    for (int mr = 0; mr < 2; ++mr) {
        // ---- Q (scaled q -> diag, in registers) ----
        f32x4 aq[4];
#pragma unroll
        for (int nc = 0; nc < 4; ++nc) aq[nc] = (f32x4){0.f,0.f,0.f,0.f};
#pragma unroll
        for (int kk = 0; kk < 4; ++kk) {
            short8 bq4[4];
#pragma unroll
            for (int nc = 0; nc < 4; ++nc)
                bq4[nc] = *(const short8*)&wqst[(w * 64 + nc * 16 + li) * 128 + kk * 32 + lg * 8];
#pragma unroll
            for (int nc = 0; nc < 4; ++nc) aq[nc] = MFMA16(af[mr][kk], bq4[nc], aq[nc]);
        }
        float dg0[4], dg1[4];
#pragma unroll
        for (int r = 0; r < 4; ++r) {
            const float v0 = aq[0][r] + bq_r[0], v1 = aq[1][r] + bq_r[1];
            const float v2 = aq[2][r] + bq_r[2], v3 = aq[3][r] + bq_r[3];
            dg0[r] = 0.5f * bsum16(v0 * v0 + v1 * v1);
            dg1[r] = 0.5f * bsum16(v2 * v2 + v3 * v3);
        }
        // ---- QD per head half: qdash -> qp (per-wave LDS region) + zden ----
        float zd[2][4];
#pragma unroll
        for (int hf = 0; hf < 2; ++hf) {
            f32x4 ad[4];
#pragma unroll
            for (int nc = 0; nc < 4; ++nc) ad[nc] = (f32x4){0.f,0.f,0.f,0.f};
#pragma unroll
            for (int kk = 0; kk < 4; ++kk) {
                short8 bd4[4];
#pragma unroll
                for (int nc = 0; nc < 4; ++nc)
                    bd4[nc] = *(const short8*)&w2qt[(w * 128 + (hf * 4 + nc) * 16 + li) * 128 + kk * 32 + lg * 8];
#pragma unroll
                for (int nc = 0; nc < 4; ++nc) ad[nc] = MFMA16(af[mr][kk], bd4[nc], ad[nc]);
            }
#pragma unroll
            for (int r = 0; r < 4; ++r) {
                float vv[4];
#pragma unroll
                for (int nc = 0; nc < 4; ++nc) vv[nc] = ad[nc][r] + b2_r[hf * 4 + nc];
                float mx = fmaxf(fmaxf(vv[0], vv[1]), fmaxf(vv[2], vv[3]));
                mx = bmax16(mx);
                const float dgh = hf ? dg1[r] : dg0[r];
                const int rr = lg * 4 + r;
                float z = 0.f;
#pragma unroll
                for (int nc = 0; nc < 4; ++nc) {
                    const float e = RATIO * (__expf(vv[nc] - dgh - mx) + KEPS);
                    z = fmaf(e, ksv[hf * 4 + nc], z);
                    const unsigned pe = (unsigned)(unsigned short)f2bf(e);
                    const unsigned po = (unsigned)__shfl_xor((int)pe, 1);
                    if (!(li & 1))
                        *(unsigned*)(smem + 16384 + w * 4096 + rr * 256 +
                            ((hf * 128 + nc * 32 + 2 * li) ^ ((rr & 7) << 4))) = pe | (po << 16);
                }
                zd[hf][r] = bsum16(z);
            }
        }
        // ---- Z: z = (qp @ kvsT) / zden (heads 2w, 2w+1), per-wave qp ----
        f32x4 az[2][2];
#pragma unroll
        for (int hi = 0; hi < 2; ++hi)
#pragma unroll
            for (int nc = 0; nc < 2; ++nc) az[hi][nc] = (f32x4){0.f,0.f,0.f,0.f};
#pragma unroll
        for (int hi = 0; hi < 2; ++hi) {
            const int h = 2 * w + hi;
#pragma unroll
            for (int kk = 0; kk < 2; ++kk) {
                const short8 aa = *(const short8*)(smem + 16384 + w * 4096 + li * 256 +
                                  ((hi * 128 + kk * 64 + lg * 16) ^ ((li & 7) << 4)));
                short8 bb[2];
#pragma unroll
                for (int nc = 0; nc < 2; ++nc)
                    bb[nc] = *(const short8*)&kvst[(h * 32 + nc * 16 + li) * 64 + kk * 32 + lg * 8];
#pragma unroll
                for (int nc = 0; nc < 2; ++nc) az[hi][nc] = MFMA16(aa, bb[nc], az[hi][nc]);
            }
        }
#pragma unroll
        for (int hi = 0; hi < 2; ++hi)
#pragma unroll
            for (int nc = 0; nc < 2; ++nc)
#pragma unroll
                for (int r = 0; r < 4; ++r) {
                    const int row = mr * 16 + lg * 4 + r;
                    const float zv = az[hi][nc][r] / zd[hi][r];
                    const unsigned pe = (unsigned)(unsigned short)f2bf(zv);
                    const unsigned po = (unsigned)__shfl_xor((int)pe, 1);
                    if (!(li & 1))
                        *(unsigned*)(smem + row * 512 +
                            (((2 * w + hi) * 64 + nc * 32 + 2 * li) ^ ((row & 7) << 4))) = pe | (po << 16);
                }
    }
    __syncthreads();   // zs complete (cross-wave)
    // ---- O: x_next = z @ WoT; out = a2*x + bc*(x_next + bo) ----
    f32x4 ao[2][2];
#pragma unroll
    for (int mr = 0; mr < 2; ++mr)
#pragma unroll
        for (int nc = 0; nc < 2; ++nc) ao[mr][nc] = (f32x4){0.f,0.f,0.f,0.f};
#pragma unroll
    for (int kk = 0; kk < 8; ++kk) {
        short8 aa[2], bb[2];
#pragma unroll
        for (int mr = 0; mr < 2; ++mr) {
            const int row = mr * 16 + li;
            aa[mr] = *(const short8*)(smem + row * 512 +
                      ((kk * 64 + lg * 16) ^ ((row & 7) << 4)));
        }
#pragma unroll
        for (int nc = 0; nc < 2; ++nc)
            bb[nc] = *(const short8*)&wot[(w * 32 + nc * 16 + li) * 256 + kk * 32 + lg * 8];
#pragma unroll
        for (int mr = 0; mr < 2; ++mr)
#pragma unroll
            for (int nc = 0; nc < 2; ++nc) ao[mr][nc] = MFMA16(aa[mr], bb[nc], ao[mr][nc]);
    }
#pragma unroll
    for (int mr = 0; mr < 2; ++mr)
#pragma unroll
        for (int nc = 0; nc < 2; ++nc)
#pragma unroll
            for (int r = 0; r < 4; ++r) {
                const int n = n0 + mr * 16 + lg * 4 + r;
                const int c = w * 32 + nc * 16 + li;
                const float xn = ao[mr][nc][r] + bo_r[nc];
                out[(size_t)n * 128 + c] = a2 * x[(size_t)n * 128 + c] + bc * xn;
            }
}

extern "C" void kernel_launch(void* const* d_in, const int* in_sizes, int n_in,
                              void* d_out, int out_size, void* d_ws, size_t ws_size,
                              hipStream_t stream) {
    (void)in_sizes; (void)n_in; (void)out_size;
    const float* x    = (const float*)d_in[0];
    const float* Wq_w = (const float*)d_in[2];
    const float* Wq_b = (const float*)d_in[3];
    const float* Wk_w = (const float*)d_in[4];
    const float* Wk_b = (const float*)d_in[5];
    const float* Wv_w = (const float*)d_in[6];
    const float* Wv_b = (const float*)d_in[7];
    const float* Wo_w = (const float*)d_in[8];
    const float* Wo_b = (const float*)d_in[9];
    const float* alpha= (const float*)d_in[10];
    const float* beta = (const float*)d_in[11];
    const float* proj = (const float*)d_in[12];
    float* out = (float*)d_out;
    float* ws  = (float*)d_ws;

    float* kmax     = ws + WS_KMAX;
    float* partials = ws + WS_PART;
    const size_t availf = (ws_size / 4 > (size_t)WS_PART) ? (ws_size / 4 - WS_PART) : 0;
    int nb = (int)(availf / 16896);
    if (nb > 625) nb = 625;
    if (nb < 1) nb = 1;

    init_kernel<<<1, 64, 0, stream>>>(kmax);
    fold_kernel<<<258, 256, 0, stream>>>(Wq_w, Wq_b, proj, ws + WS_W2Q, ws + WS_B2Q);
    fold_kernel<<<258, 256, 0, stream>>>(Wk_w, Wk_b, proj, ws + WS_W2K, ws + WS_B2K);
    prep_kernel<<<1027, 256, 0, stream>>>(Wq_w, Wq_b, Wk_w, Wk_b, Wv_w, Wv_b, Wo_w, ws);
    kmax_mfma_kernel<<<1563, 256, 0, stream>>>(x, ws, kmax);
    kvs_mfma_kernel<<<nb, 256, 0, stream>>>(x, ws, partials, nb);
    reduce_kernel<<<66, 256, 0, stream>>>(partials, ws, nb);
    out_mfma_kernel<<<3125, 256, 0, stream>>>(x, ws, alpha, beta, Wo_b, out);
}

// Round 5
// 626.854 us; speedup vs baseline: 1.3227x; 1.3227x over previous
//
#include <hip/hip_runtime.h>
#include <math.h>

#define NN 100000
#define SCALE 0.8408964152537145f  // inv_sqrt_tau(=2) * 32^-0.25
#define HALF_SCALE2 0.3535533905932738f // 0.5 * SCALE^2
#define RATIO 0.125f               // 64^-0.5
#define KEPS 1e-6f

// ws layout (float offsets)
#define WS_KMAX 0
#define WS_KVSKS 8          // 16384 kvs fp32 + 512 ks fp32
#define WS_KVST 16904       // kvsT bf16 [8][32][64] -> 8192 floats
#define WS_W2Q 25096        // fp32 [128][512]
#define WS_W2K 90632        // fp32 [128][512]
#define WS_B2Q 156168       // 512
#define WS_B2K 156680       // 512
#define WS_W2QT 157192      // bf16 [512][128] -> 32768 floats
#define WS_W2KT 189960      // bf16 [512][128]
#define WS_WQST 222728      // bf16 [256][128] (SCALE*Wq)^T -> 16384 floats
#define WS_WOT 239112       // bf16 [128][256] Wo^T -> 16384 floats
#define WS_BQS 255496       // 256 fp32 (SCALE*Wq_b)
#define WS_WKVT 255752      // bf16 [512][128] [Wk|Wv]^T -> 32768 floats
#define WS_BKV 288520       // 512 fp32 [bk|bv]
#define WS_RED2 289032      // 8*16896 fp32 stage-2 reduce partials
#define WS_PART 424200      // nb * 16896

typedef __attribute__((ext_vector_type(8))) short short8;
typedef __attribute__((ext_vector_type(4))) float f32x4;

#define MFMA16(a, b, c) __builtin_amdgcn_mfma_f32_16x16x32_bf16((a), (b), (c), 0, 0, 0)

__device__ __forceinline__ short f2bf(float f) {
    union { float f; unsigned u; } a; a.f = f;
    unsigned r = a.u + 0x7fffu + ((a.u >> 16) & 1u);
    return (short)(r >> 16);
}
__device__ __forceinline__ float bf2f(short s) {
    union { float f; unsigned u; } a; a.u = ((unsigned)(unsigned short)s) << 16;
    return a.f;
}

__device__ __forceinline__ float bsum16(float v) {
    v += __shfl_xor(v, 1); v += __shfl_xor(v, 2);
    v += __shfl_xor(v, 4); v += __shfl_xor(v, 8);
    return v;
}
__device__ __forceinline__ float bmax16(float v) {
    v = fmaxf(v, __shfl_xor(v, 1)); v = fmaxf(v, __shfl_xor(v, 2));
    v = fmaxf(v, __shfl_xor(v, 4)); v = fmaxf(v, __shfl_xor(v, 8));
    return v;
}

__device__ __forceinline__ void atomicMaxFloat(float* addr, float val) {
    int* ai = (int*)addr;
    int cur = *((volatile int*)ai);
    while (val > __int_as_float(cur)) {
        int assumed = cur;
        cur = atomicCAS(ai, assumed, __float_as_int(val));
        if (cur == assumed) break;
    }
}

// ---------- fold ----------
__global__ __launch_bounds__(256) void fold_kernel(
    const float* __restrict__ W, const float* __restrict__ b,
    const float* __restrict__ proj,
    float* __restrict__ W2, float* __restrict__ b2)
{
    const int idx = blockIdx.x * 256 + threadIdx.x;
    if (idx >= 129 * 512) return;
    const int row = idx >> 9;
    const int col = idx & 511;
    const int h = col >> 6, m = col & 63;
    const float* src = (row < 128) ? (W + row * 256 + h * 32) : (b + h * 32);
    float s = 0.f;
#pragma unroll
    for (int d = 0; d < 32; ++d) s = fmaf(src[d], proj[m * 32 + d], s);
    s *= SCALE;
    if (row < 128) W2[row * 512 + col] = s;
    else           b2[col] = s;
}

// ---------- prep ----------
__global__ __launch_bounds__(256) void prep_kernel(
    const float* __restrict__ Wq_w, const float* __restrict__ Wq_b,
    const float* __restrict__ Wk_w, const float* __restrict__ Wk_b,
    const float* __restrict__ Wv_w, const float* __restrict__ Wv_b,
    const float* __restrict__ Wo_w, float* __restrict__ ws)
{
    int idx = blockIdx.x * 256 + threadIdx.x;
    if (idx < 32768) {
        int c = idx >> 7, k = idx & 127;
        ((short*)(ws + WS_WQST))[idx] = f2bf(SCALE * Wq_w[k * 256 + c]);
        return;
    }
    idx -= 32768;
    if (idx < 65536) {
        int c = idx >> 7, k = idx & 127;
        ((short*)(ws + WS_W2QT))[idx] = f2bf(ws[WS_W2Q + k * 512 + c]);
        return;
    }
    idx -= 65536;
    if (idx < 65536) {
        int c = idx >> 7, k = idx & 127;
        ((short*)(ws + WS_W2KT))[idx] = f2bf(ws[WS_W2K + k * 512 + c]);
        return;
    }
    idx -= 65536;
    if (idx < 32768) {
        int o = idx >> 8, c = idx & 255;
        ((short*)(ws + WS_WOT))[idx] = f2bf(Wo_w[c * 128 + o]);
        return;
    }
    idx -= 32768;
    if (idx < 256) { ws[WS_BQS + idx] = SCALE * Wq_b[idx]; return; }
    idx -= 256;
    if (idx < 65536) {
        int c = idx >> 7, k = idx & 127;
        ((short*)(ws + WS_WKVT))[idx] =
            f2bf(c < 256 ? Wk_w[k * 256 + c] : Wv_w[k * 256 + (c - 256)]);
        return;
    }
    idx -= 65536;
    if (idx < 512) ws[WS_BKV + idx] = (idx < 256) ? Wk_b[idx] : Wv_b[idx - 256];
}

__global__ void init_kernel(float* kmax) {
    if (threadIdx.x < 8) kmax[threadIdx.x] = -1e30f;
}

// ---------- kmax: global per-head max of kdash (64 rows/block, B-hoisted) ----------
__global__ __launch_bounds__(256) void kmax_mfma_kernel(
    const float* __restrict__ x, const float* __restrict__ ws, float* __restrict__ kmax)
{
    __shared__ char smem[16384];
    const short* w2kt = (const short*)(ws + WS_W2KT);
    const float* b2k = ws + WS_B2K;
    const int t = threadIdx.x, w = t >> 6, l = t & 63, lg = l >> 4, li = l & 15;
    float b2r[8];
#pragma unroll
    for (int nc = 0; nc < 8; ++nc) b2r[nc] = b2k[w * 128 + nc * 16 + li];
    float mx0 = -1e30f, mx1 = -1e30f;

    const int n0 = blockIdx.x * 64;
    {
        const int sr = t >> 2, sp = t & 3;
        float f[32];
        if (n0 + sr < NN) {
            const float* gp = x + (size_t)(n0 + sr) * 128 + sp * 32;
#pragma unroll
            for (int i = 0; i < 8; ++i) {
                float4 v = *(const float4*)(gp + i * 4);
                f[i * 4] = v.x; f[i * 4 + 1] = v.y; f[i * 4 + 2] = v.z; f[i * 4 + 3] = v.w;
            }
        } else {
#pragma unroll
            for (int i = 0; i < 32; ++i) f[i] = 0.f;
        }
        const int rb = sr * 256, sw = (sr & 7) << 4;
#pragma unroll
        for (int j = 0; j < 4; ++j) {
            short8 s;
#pragma unroll
            for (int e = 0; e < 8; ++e) s[e] = f2bf(f[j * 8 + e]);
            *(short8*)(smem + rb + ((sp * 64 + 16 * j) ^ sw)) = s;
        }
    }
    __syncthreads();
#pragma unroll
    for (int hf = 0; hf < 2; ++hf) {
        short8 Bf[16];
#pragma unroll
        for (int kk = 0; kk < 4; ++kk)
#pragma unroll
            for (int nc = 0; nc < 4; ++nc)
                Bf[kk * 4 + nc] = *(const short8*)&w2kt[(w * 128 + (hf * 4 + nc) * 16 + li) * 128 + kk * 32 + lg * 8];
#pragma unroll
        for (int mr = 0; mr < 4; ++mr) {
            f32x4 acc[4];
#pragma unroll
            for (int nc = 0; nc < 4; ++nc) acc[nc] = (f32x4){0.f, 0.f, 0.f, 0.f};
#pragma unroll
            for (int kk = 0; kk < 4; ++kk) {
                const int row = mr * 16 + li;
                const short8 a = *(const short8*)(smem + row * 256 + (((kk * 32 + lg * 8) * 2) ^ ((row & 7) << 4)));
#pragma unroll
                for (int nc = 0; nc < 4; ++nc) acc[nc] = MFMA16(a, Bf[kk * 4 + nc], acc[nc]);
            }
#pragma unroll
            for (int r = 0; r < 4; ++r) {
                const int row = mr * 16 + lg * 4 + r;
                if (n0 + row < NN) {
#pragma unroll
                    for (int nc = 0; nc < 4; ++nc) {
                        const float v = acc[nc][r] + b2r[hf * 4 + nc];
                        if (hf == 0) mx0 = fmaxf(mx0, v); else mx1 = fmaxf(mx1, v);
                    }
                }
            }
        }
    }
    mx0 = bmax16(mx0); mx0 = fmaxf(mx0, __shfl_xor(mx0, 16)); mx0 = fmaxf(mx0, __shfl_xor(mx0, 32));
    mx1 = bmax16(mx1); mx1 = fmaxf(mx1, __shfl_xor(mx1, 16)); mx1 = fmaxf(mx1, __shfl_xor(mx1, 32));
    if (l == 0) {
        atomicMaxFloat(&kmax[2 * w], mx0);
        atomicMaxFloat(&kmax[2 * w + 1], mx1);
    }
}

// ---------- kvs via MFMA (32 rows/tile, persistent, B-hoisted GEMMs) ----------
__global__ __launch_bounds__(256) void kvs_mfma_kernel(
    const float* __restrict__ x, const float* __restrict__ ws,
    float* __restrict__ partials, int nb)
{
    __shared__ char smem[41984];
    const short* wkvt = (const short*)(ws + WS_WKVT);
    const short* w2kt = (const short*)(ws + WS_W2KT);
    const float* bkv  = ws + WS_BKV;
    const float* b2k  = ws + WS_B2K;
    const float* kmax = ws + WS_KMAX;
    float* diagL = (float*)(smem + 40960);

    const int t = threadIdx.x, w = t >> 6, l = t & 63, lg = l >> 4, li = l & 15;
    float bkv_r[8], b2_r[8];
#pragma unroll
    for (int nc = 0; nc < 8; ++nc) {
        bkv_r[nc] = bkv[w * 128 + nc * 16 + li];
        b2_r[nc]  = b2k[w * 128 + nc * 16 + li];
    }
    const float km0 = kmax[2 * w], km1 = kmax[2 * w + 1];

    f32x4 ak[2][4][2];
#pragma unroll
    for (int hi = 0; hi < 2; ++hi)
#pragma unroll
        for (int mr = 0; mr < 4; ++mr)
#pragma unroll
            for (int nc = 0; nc < 2; ++nc) ak[hi][mr][nc] = (f32x4){0.f,0.f,0.f,0.f};
    float ksacc[8];
#pragma unroll
    for (int nc = 0; nc < 8; ++nc) ksacc[nc] = 0.f;

    for (int tile = blockIdx.x; tile < 3125; tile += nb) {
        const int n0 = tile * 32;
        __syncthreads();
        {
            const int sr = t >> 3, sp = t & 7;
            const float* gp = x + (size_t)(n0 + sr) * 128 + sp * 16;
            float f[16];
#pragma unroll
            for (int i = 0; i < 4; ++i) {
                float4 v = *(const float4*)(gp + i * 4);
                f[i*4] = v.x; f[i*4+1] = v.y; f[i*4+2] = v.z; f[i*4+3] = v.w;
            }
            const int rb = sr * 256, sw = (sr & 7) << 4;
#pragma unroll
            for (int j = 0; j < 2; ++j) {
                short8 s;
#pragma unroll
                for (int e = 0; e < 8; ++e) s[e] = f2bf(f[j * 8 + e]);
                *(short8*)(smem + rb + ((sp * 32 + 16 * j) ^ sw)) = s;
            }
        }
        __syncthreads();
        short8 af[2][4];
#pragma unroll
        for (int mr = 0; mr < 2; ++mr) {
            const int row = mr * 16 + li, rb = row * 256, sw = (row & 7) << 4;
#pragma unroll
            for (int kk = 0; kk < 4; ++kk)
                af[mr][kk] = *(const short8*)(smem + rb + (((kk * 32 + lg * 8) * 2) ^ sw));
        }
        // ---- GEMM1: [k|v] = x @ [Wk|Wv] (B hoisted per hf) ----
#pragma unroll
        for (int hf = 0; hf < 2; ++hf) {
            short8 Bf[16];
#pragma unroll
            for (int kk = 0; kk < 4; ++kk)
#pragma unroll
                for (int nc = 0; nc < 4; ++nc)
                    Bf[kk * 4 + nc] = *(const short8*)&wkvt[(w * 128 + (hf * 4 + nc) * 16 + li) * 128 + kk * 32 + lg * 8];
            f32x4 acc[2][4];
#pragma unroll
            for (int mr = 0; mr < 2; ++mr)
#pragma unroll
                for (int nc = 0; nc < 4; ++nc) acc[mr][nc] = (f32x4){0.f,0.f,0.f,0.f};
#pragma unroll
            for (int kk = 0; kk < 4; ++kk)
#pragma unroll
                for (int mr = 0; mr < 2; ++mr)
#pragma unroll
                    for (int nc = 0; nc < 4; ++nc) acc[mr][nc] = MFMA16(af[mr][kk], Bf[kk * 4 + nc], acc[mr][nc]);
            if (w < 2) {
#pragma unroll
                for (int mr = 0; mr < 2; ++mr)
#pragma unroll
                    for (int r = 0; r < 4; ++r) {
                        const int n = mr * 16 + lg * 4 + r;
#pragma unroll
                        for (int jj = 0; jj < 2; ++jj) {
                            const float v0 = acc[mr][2*jj][r]   + bkv_r[hf*4 + 2*jj];
                            const float v1 = acc[mr][2*jj+1][r] + bkv_r[hf*4 + 2*jj+1];
                            const float s = bsum16(v0 * v0 + v1 * v1);
                            if (li == 0) diagL[n * 8 + w * 4 + hf * 2 + jj] = HALF_SCALE2 * s;
                        }
                    }
            } else {
#pragma unroll
                for (int mr = 0; mr < 2; ++mr)
#pragma unroll
                    for (int nc = 0; nc < 4; ++nc) {
                        short4 s4;
                        s4.x = f2bf(acc[mr][nc][0] + bkv_r[hf*4+nc]);
                        s4.y = f2bf(acc[mr][nc][1] + bkv_r[hf*4+nc]);
                        s4.z = f2bf(acc[mr][nc][2] + bkv_r[hf*4+nc]);
                        s4.w = f2bf(acc[mr][nc][3] + bkv_r[hf*4+nc]);
                        const int row = (w - 2) * 128 + (hf * 4 + nc) * 16 + li;
                        const int b = 32 * mr + 8 * lg;
                        *(short4*)(smem + 24576 + row * 64 +
                                   ((((b >> 4) ^ ((row >> 1) & 3)) << 4) | (b & 15))) = s4;
                    }
            }
        }
        __syncthreads();
        // ---- per head: GEMM2 (B hoisted) -> kp -> kpT, then GEMM3 ----
#pragma unroll
        for (int hf = 0; hf < 2; ++hf) {
            short8 Bf[16];
#pragma unroll
            for (int kk = 0; kk < 4; ++kk)
#pragma unroll
                for (int nc = 0; nc < 4; ++nc)
                    Bf[kk * 4 + nc] = *(const short8*)&w2kt[(w * 128 + (hf * 4 + nc) * 16 + li) * 128 + kk * 32 + lg * 8];
            f32x4 acd[2][4];
#pragma unroll
            for (int mr = 0; mr < 2; ++mr)
#pragma unroll
                for (int nc = 0; nc < 4; ++nc) acd[mr][nc] = (f32x4){0.f,0.f,0.f,0.f};
#pragma unroll
            for (int kk = 0; kk < 4; ++kk)
#pragma unroll
                for (int mr = 0; mr < 2; ++mr)
#pragma unroll
                    for (int nc = 0; nc < 4; ++nc) acd[mr][nc] = MFMA16(af[mr][kk], Bf[kk * 4 + nc], acd[mr][nc]);
            const float km = hf ? km1 : km0;
            const int hh = 2 * w + hf;
#pragma unroll
            for (int mr = 0; mr < 2; ++mr)
#pragma unroll
                for (int nc = 0; nc < 4; ++nc) {
                    short4 s4;
#pragma unroll
                    for (int r = 0; r < 4; ++r) {
                        const int n = mr * 16 + lg * 4 + r;
                        const float val = acd[mr][nc][r] + b2_r[hf * 4 + nc];
                        const float kp = RATIO * (__expf(val - diagL[n * 8 + hh] - km) + KEPS);
                        const short sb = f2bf(kp);
                        ksacc[hf * 4 + nc] += bf2f(sb);
                        if (r == 0) s4.x = sb; else if (r == 1) s4.y = sb;
                        else if (r == 2) s4.z = sb; else s4.w = sb;
                    }
                    const int mrow = nc * 16 + li;
                    const int b = 32 * mr + 8 * lg;
                    *(short4*)(smem + 8192 + w * 4096 + mrow * 64 +
                               ((((b >> 4) ^ ((mrow >> 1) & 3)) << 4) | (b & 15))) = s4;
                }
            short8 aa[4], bv[2];
#pragma unroll
            for (int mr = 0; mr < 4; ++mr) {
                const int row = mr * 16 + li;
                aa[mr] = *(const short8*)(smem + 8192 + w * 4096 + row * 64 +
                                          ((lg ^ ((row >> 1) & 3)) << 4));
            }
#pragma unroll
            for (int nc = 0; nc < 2; ++nc) {
                const int vrow = hh * 32 + nc * 16 + li;
                bv[nc] = *(const short8*)(smem + 24576 + vrow * 64 +
                                          ((lg ^ ((vrow >> 1) & 3)) << 4));
            }
#pragma unroll
            for (int mr = 0; mr < 4; ++mr)
#pragma unroll
                for (int nc = 0; nc < 2; ++nc)
                    ak[hf][mr][nc] = MFMA16(aa[mr], bv[nc], ak[hf][mr][nc]);
        }
    }
    float* pb = partials + (size_t)blockIdx.x * 16896;
#pragma unroll
    for (int hi = 0; hi < 2; ++hi) {
        const int h = 2 * w + hi;
#pragma unroll
        for (int mr = 0; mr < 4; ++mr)
#pragma unroll
            for (int nc = 0; nc < 2; ++nc)
#pragma unroll
                for (int r = 0; r < 4; ++r) {
                    const int m = mr * 16 + lg * 4 + r;
                    const int d = nc * 16 + li;
                    pb[(h * 64 + m) * 32 + d] = ak[hi][mr][nc][r];
                }
    }
#pragma unroll
    for (int nc = 0; nc < 8; ++nc) {
        float s = ksacc[nc];
        s += __shfl_xor(s, 16); s += __shfl_xor(s, 32);
        if (lg == 0) {
            const int h = 2 * w + (nc >> 2);
            const int m = (nc & 3) * 16 + li;
            pb[16384 + h * 64 + m] = s;
        }
    }
}

// ---------- two-stage deterministic reduce ----------
__global__ __launch_bounds__(256) void reduce1_kernel(
    const float* __restrict__ partials, float* __restrict__ red2, int nb)
{
    const int b = blockIdx.x;
    const int part = b & 7, grp = b >> 3;
    const int idx = grp * 256 + threadIdx.x;
    if (idx >= 16896) return;
    const int per = (nb + 7) >> 3;
    const int lo = part * per;
    const int hi = (lo + per < nb) ? (lo + per) : nb;
    float s = 0.f;
    for (int q = lo; q < hi; ++q) s += partials[(size_t)q * 16896 + idx];
    red2[part * 16896 + idx] = s;
}

__global__ __launch_bounds__(256) void reduce2_kernel(
    const float* __restrict__ red2, float* __restrict__ ws)
{
    const int idx = blockIdx.x * 256 + threadIdx.x;
    if (idx >= 16896) return;
    float s = 0.f;
#pragma unroll
    for (int p = 0; p < 8; ++p) s += red2[p * 16896 + idx];
    ws[WS_KVSKS + idx] = s;
    if (idx < 16384) {
        const int h = idx >> 11, m = (idx >> 5) & 63, d = idx & 31;
        ((short*)(ws + WS_KVST))[(h * 32 + d) * 64 + m] = f2bf(s);
    }
}

// ---------- fused MFMA output kernel: 64 rows/block, B-hoisted ----------
// smem: [0,16384) xs [64][256B]; [16384,49152) zs [64][512B]; [49152,57344) qp per-wave 2KB
__global__ __launch_bounds__(256) void out_mfma_kernel(
    const float* __restrict__ x, const float* __restrict__ ws,
    const float* __restrict__ alpha, const float* __restrict__ beta,
    const float* __restrict__ Wo_b, float* __restrict__ out)
{
    __shared__ char smem[57344];
    const short* wqst = (const short*)(ws + WS_WQST);
    const short* w2qt = (const short*)(ws + WS_W2QT);
    const short* wot  = (const short*)(ws + WS_WOT);
    const short* kvst = (const short*)(ws + WS_KVST);
    const float* bqs  = ws + WS_BQS;
    const float* b2q  = ws + WS_B2Q;
    const float* ksum = ws + WS_KVSKS + 16384;

    const int t = threadIdx.x, w = t >> 6, l = t & 63, lg = l >> 4, li = l & 15;
    const float a_ = __expf(alpha[0]), b_ = __expf(beta[0]);
    const float a2 = a_ * a_, bc = b_ * (a_ + 1.f);
    char* qpb = smem + 49152 + w * 2048;

    float bq_r[4], b2_r[8], ksv[8], bo_r[2];
#pragma unroll
    for (int nc = 0; nc < 4; ++nc) bq_r[nc] = bqs[w * 64 + nc * 16 + li];
#pragma unroll
    for (int nc = 0; nc < 8; ++nc) {
        const int c = w * 128 + nc * 16 + li;
        b2_r[nc] = b2q[c]; ksv[nc] = ksum[c];
    }
#pragma unroll
    for (int nc = 0; nc < 2; ++nc) bo_r[nc] = Wo_b[w * 32 + nc * 16 + li];

    const int n0 = blockIdx.x * 64;
    // ---- stage x[64][128] -> bf16 swizzled ----
    {
        const int sr = t >> 2, sp = t & 3;
        float f[32];
        if (n0 + sr < NN) {
            const float* gp = x + (size_t)(n0 + sr) * 128 + sp * 32;
#pragma unroll
            for (int i = 0; i < 8; ++i) {
                float4 v = *(const float4*)(gp + i * 4);
                f[i*4] = v.x; f[i*4+1] = v.y; f[i*4+2] = v.z; f[i*4+3] = v.w;
            }
        } else {
#pragma unroll
            for (int i = 0; i < 32; ++i) f[i] = 0.f;
        }
        const int rb = sr * 256, sw = (sr & 7) << 4;
#pragma unroll
        for (int j = 0; j < 4; ++j) {
            short8 s;
#pragma unroll
            for (int e = 0; e < 8; ++e) s[e] = f2bf(f[j * 8 + e]);
            *(short8*)(smem + rb + ((sp * 64 + 16 * j) ^ sw)) = s;
        }
    }
    __syncthreads();
    // ---- Q phase: diag for all 64 rows (B hoisted) ----
    float dg[4][2][4];   // [mr][hf][r]
    {
        short8 Bf[16];
#pragma unroll
        for (int kk = 0; kk < 4; ++kk)
#pragma unroll
            for (int nc = 0; nc < 4; ++nc)
                Bf[kk * 4 + nc] = *(const short8*)&wqst[(w * 64 + nc * 16 + li) * 128 + kk * 32 + lg * 8];
#pragma unroll
        for (int mr = 0; mr < 4; ++mr) {
            f32x4 aq[4];
#pragma unroll
            for (int nc = 0; nc < 4; ++nc) aq[nc] = (f32x4){0.f,0.f,0.f,0.f};
#pragma unroll
            for (int kk = 0; kk < 4; ++kk) {
                const int row = mr * 16 + li;
                const short8 a = *(const short8*)(smem + row * 256 + (((kk * 32 + lg * 8) * 2) ^ ((row & 7) << 4)));
#pragma unroll
                for (int nc = 0; nc < 4; ++nc) aq[nc] = MFMA16(a, Bf[kk * 4 + nc], aq[nc]);
            }
#pragma unroll
            for (int r = 0; r < 4; ++r) {
                const float v0 = aq[0][r] + bq_r[0], v1 = aq[1][r] + bq_r[1];
                const float v2 = aq[2][r] + bq_r[2], v3 = aq[3][r] + bq_r[3];
                dg[mr][0][r] = 0.5f * bsum16(v0 * v0 + v1 * v1);
                dg[mr][1][r] = 0.5f * bsum16(v2 * v2 + v3 * v3);
            }
        }
    }
    // ---- QD + Z per head (B hoisted per hf; qp per-wave 2KB reused) ----
#pragma unroll
    for (int hf = 0; hf < 2; ++hf) {
        short8 Bf[16];
#pragma unroll
        for (int kk = 0; kk < 4; ++kk)
#pragma unroll
            for (int nc = 0; nc < 4; ++nc)
                Bf[kk * 4 + nc] = *(const short8*)&w2qt[(w * 128 + (hf * 4 + nc) * 16 + li) * 128 + kk * 32 + lg * 8];
        short8 Kf[4];
#pragma unroll
        for (int kk = 0; kk < 2; ++kk)
#pragma unroll
            for (int nc = 0; nc < 2; ++nc)
                Kf[kk * 2 + nc] = *(const short8*)&kvst[((2 * w + hf) * 32 + nc * 16 + li) * 64 + kk * 32 + lg * 8];
#pragma unroll
        for (int mr = 0; mr < 4; ++mr) {
            f32x4 ad[4];
#pragma unroll
            for (int nc = 0; nc < 4; ++nc) ad[nc] = (f32x4){0.f,0.f,0.f,0.f};
#pragma unroll
            for (int kk = 0; kk < 4; ++kk) {
                const int row = mr * 16 + li;
                const short8 a = *(const short8*)(smem + row * 256 + (((kk * 32 + lg * 8) * 2) ^ ((row & 7) << 4)));
#pragma unroll
                for (int nc = 0; nc < 4; ++nc) ad[nc] = MFMA16(a, Bf[kk * 4 + nc], ad[nc]);
            }
            float zd[4];
#pragma unroll
            for (int r = 0; r < 4; ++r) {
                float vv[4];
#pragma unroll
                for (int nc = 0; nc < 4; ++nc) vv[nc] = ad[nc][r] + b2_r[hf * 4 + nc];
                float mx = fmaxf(fmaxf(vv[0], vv[1]), fmaxf(vv[2], vv[3]));
                mx = bmax16(mx);
                const float dgh = dg[mr][hf][r];
                const int rr = lg * 4 + r;
                float z = 0.f;
#pragma unroll
                for (int nc = 0; nc < 4; ++nc) {
                    const float e = RATIO * (__expf(vv[nc] - dgh - mx) + KEPS);
                    z = fmaf(e, ksv[hf * 4 + nc], z);
                    const unsigned pe = (unsigned)(unsigned short)f2bf(e);
                    const unsigned po = (unsigned)__shfl_xor((int)pe, 1);
                    if (!(li & 1))
                        *(unsigned*)(qpb + rr * 128 +
                            ((nc * 32 + 2 * li) ^ ((rr & 7) << 4))) = pe | (po << 16);
                }
                zd[r] = bsum16(z);
            }
            // Z for (hf, mr): az = qp @ kvsT
            f32x4 az[2];
#pragma unroll
            for (int nc = 0; nc < 2; ++nc) az[nc] = (f32x4){0.f,0.f,0.f,0.f};
#pragma unroll
            for (int kk = 0; kk < 2; ++kk) {
                const short8 aa = *(const short8*)(qpb + li * 128 +
                                  ((kk * 64 + lg * 16) ^ ((li & 7) << 4)));
#pragma unroll
                for (int nc = 0; nc < 2; ++nc) az[nc] = MFMA16(aa, Kf[kk * 2 + nc], az[nc]);
            }
#pragma unroll
            for (int nc = 0; nc < 2; ++nc)
#pragma unroll
                for (int r = 0; r < 4; ++r) {
                    const int row = mr * 16 + lg * 4 + r;
                    const float zv = az[nc][r] / zd[r];
                    const unsigned pe = (unsigned)(unsigned short)f2bf(zv);
                    const unsigned po = (unsigned)__shfl_xor((int)pe, 1);
                    if (!(li & 1))
                        *(unsigned*)(smem + 16384 + row * 512 +
                            (((2 * w + hf) * 64 + nc * 32 + 2 * li) ^ ((row & 7) << 4))) = pe | (po << 16);
                }
        }
    }
    // ---- O weights: issue loads before barrier ----
    short8 Bo[16];
#pragma unroll
    for (int kk = 0; kk < 8; ++kk)
#pragma unroll
        for (int nc = 0; nc < 2; ++nc)
            Bo[kk * 2 + nc] = *(const short8*)&wot[(w * 32 + nc * 16 + li) * 256 + kk * 32 + lg * 8];
    __syncthreads();   // zs complete
    // ---- O: x_next = z @ WoT ----
    f32x4 ao[4][2];
#pragma unroll
    for (int mr = 0; mr < 4; ++mr)
#pragma unroll
        for (int nc = 0; nc < 2; ++nc) ao[mr][nc] = (f32x4){0.f,0.f,0.f,0.f};
#pragma unroll
    for (int mr = 0; mr < 4; ++mr)
#pragma unroll
        for (int kk = 0; kk < 8; ++kk) {
            const int row = mr * 16 + li;
            const short8 aa = *(const short8*)(smem + 16384 + row * 512 +
                              ((kk * 64 + lg * 16) ^ ((row & 7) << 4)));
#pragma unroll
            for (int nc = 0; nc < 2; ++nc) ao[mr][nc] = MFMA16(aa, Bo[kk * 2 + nc], ao[mr][nc]);
        }
#pragma unroll
    for (int mr = 0; mr < 4; ++mr)
#pragma unroll
        for (int nc = 0; nc < 2; ++nc)
#pragma unroll
            for (int r = 0; r < 4; ++r) {
                const int n = n0 + mr * 16 + lg * 4 + r;
                if (n < NN) {
                    const int c = w * 32 + nc * 16 + li;
                    const float xn = ao[mr][nc][r] + bo_r[nc];
                    out[(size_t)n * 128 + c] = a2 * x[(size_t)n * 128 + c] + bc * xn;
                }
            }
}

extern "C" void kernel_launch(void* const* d_in, const int* in_sizes, int n_in,
                              void* d_out, int out_size, void* d_ws, size_t ws_size,
                              hipStream_t stream) {
    (void)in_sizes; (void)n_in; (void)out_size;
    const float* x    = (const float*)d_in[0];
    const float* Wq_w = (const float*)d_in[2];
    const float* Wq_b = (const float*)d_in[3];
    const float* Wk_w = (const float*)d_in[4];
    const float* Wk_b = (const float*)d_in[5];
    const float* Wv_w = (const float*)d_in[6];
    const float* Wv_b = (const float*)d_in[7];
    const float* Wo_w = (const float*)d_in[8];
    const float* Wo_b = (const float*)d_in[9];
    const float* alpha= (const float*)d_in[10];
    const float* beta = (const float*)d_in[11];
    const float* proj = (const float*)d_in[12];
    float* out = (float*)d_out;
    float* ws  = (float*)d_ws;

    float* kmax     = ws + WS_KMAX;
    float* red2     = ws + WS_RED2;
    float* partials = ws + WS_PART;
    const size_t availf = (ws_size / 4 > (size_t)WS_PART) ? (ws_size / 4 - WS_PART) : 0;
    int nb = (int)(availf / 16896);
    if (nb > 625) nb = 625;
    if (nb < 1) nb = 1;

    init_kernel<<<1, 64, 0, stream>>>(kmax);
    fold_kernel<<<258, 256, 0, stream>>>(Wq_w, Wq_b, proj, ws + WS_W2Q, ws + WS_B2Q);
    fold_kernel<<<258, 256, 0, stream>>>(Wk_w, Wk_b, proj, ws + WS_W2K, ws + WS_B2K);
    prep_kernel<<<1027, 256, 0, stream>>>(Wq_w, Wq_b, Wk_w, Wk_b, Wv_w, Wv_b, Wo_w, ws);
    kmax_mfma_kernel<<<1563, 256, 0, stream>>>(x, ws, kmax);
    kvs_mfma_kernel<<<nb, 256, 0, stream>>>(x, ws, partials, nb);
    reduce1_kernel<<<528, 256, 0, stream>>>(partials, red2, nb);
    reduce2_kernel<<<66, 256, 0, stream>>>(red2, ws);
    out_mfma_kernel<<<1563, 256, 0, stream>>>(x, ws, alpha, beta, Wo_b, out);
}

// Round 6
// 599.130 us; speedup vs baseline: 1.3839x; 1.0463x over previous
//
#include <hip/hip_runtime.h>
#include <math.h>

#define NN 100000
#define SCALE 0.8408964152537145f  // inv_sqrt_tau(=2) * 32^-0.25
#define HALF_SCALE2 0.3535533905932738f // 0.5 * SCALE^2
#define RATIO 0.125f               // 64^-0.5
#define KEPS 1e-6f

// ws layout (float offsets)
#define WS_KMAX 0
#define WS_KVSKS 8          // 16384 kvs fp32 + 512 ks fp32
#define WS_KVST 16904       // kvsT bf16 [8][32][64] -> 8192 floats
#define WS_W2Q 25096        // fp32 [128][512]
#define WS_W2K 90632        // fp32 [128][512]
#define WS_B2Q 156168       // 512
#define WS_B2K 156680       // 512
#define WS_W2QT 157192      // bf16 [512][128] -> 32768 floats
#define WS_W2KT 189960      // bf16 [512][128]
#define WS_WQST 222728      // bf16 [256][128] (SCALE*Wq)^T -> 16384 floats
#define WS_WOT 239112       // bf16 [128][256] Wo^T -> 16384 floats
#define WS_BQS 255496       // 256 fp32 (SCALE*Wq_b)
#define WS_WKVT 255752      // bf16 [512][128] [Wk|Wv]^T -> 32768 floats
#define WS_BKV 288520       // 512 fp32 [bk|bv]
#define WS_RED2 289032      // 8*16896 fp32 stage-2 reduce partials
#define WS_PART 424200      // nb * 16896

typedef __attribute__((ext_vector_type(8))) short short8;
typedef __attribute__((ext_vector_type(4))) float f32x4;

#define MFMA16(a, b, c) __builtin_amdgcn_mfma_f32_16x16x32_bf16((a), (b), (c), 0, 0, 0)

__device__ __forceinline__ short f2bf(float f) {
    union { float f; unsigned u; } a; a.f = f;
    unsigned r = a.u + 0x7fffu + ((a.u >> 16) & 1u);
    return (short)(r >> 16);
}
__device__ __forceinline__ float bf2f(short s) {
    union { float f; unsigned u; } a; a.u = ((unsigned)(unsigned short)s) << 16;
    return a.f;
}

__device__ __forceinline__ float bsum16(float v) {
    v += __shfl_xor(v, 1); v += __shfl_xor(v, 2);
    v += __shfl_xor(v, 4); v += __shfl_xor(v, 8);
    return v;
}
__device__ __forceinline__ float bmax16(float v) {
    v = fmaxf(v, __shfl_xor(v, 1)); v = fmaxf(v, __shfl_xor(v, 2));
    v = fmaxf(v, __shfl_xor(v, 4)); v = fmaxf(v, __shfl_xor(v, 8));
    return v;
}

__device__ __forceinline__ void atomicMaxFloat(float* addr, float val) {
    int* ai = (int*)addr;
    int cur = *((volatile int*)ai);
    while (val > __int_as_float(cur)) {
        int assumed = cur;
        cur = atomicCAS(ai, assumed, __float_as_int(val));
        if (cur == assumed) break;
    }
}

// ---------- fold ----------
__global__ __launch_bounds__(256) void fold_kernel(
    const float* __restrict__ W, const float* __restrict__ b,
    const float* __restrict__ proj,
    float* __restrict__ W2, float* __restrict__ b2)
{
    const int idx = blockIdx.x * 256 + threadIdx.x;
    if (idx >= 129 * 512) return;
    const int row = idx >> 9;
    const int col = idx & 511;
    const int h = col >> 6, m = col & 63;
    const float* src = (row < 128) ? (W + row * 256 + h * 32) : (b + h * 32);
    float s = 0.f;
#pragma unroll
    for (int d = 0; d < 32; ++d) s = fmaf(src[d], proj[m * 32 + d], s);
    s *= SCALE;
    if (row < 128) W2[row * 512 + col] = s;
    else           b2[col] = s;
}

// ---------- prep ----------
__global__ __launch_bounds__(256) void prep_kernel(
    const float* __restrict__ Wq_w, const float* __restrict__ Wq_b,
    const float* __restrict__ Wk_w, const float* __restrict__ Wk_b,
    const float* __restrict__ Wv_w, const float* __restrict__ Wv_b,
    const float* __restrict__ Wo_w, float* __restrict__ ws)
{
    int idx = blockIdx.x * 256 + threadIdx.x;
    if (idx < 32768) {
        int c = idx >> 7, k = idx & 127;
        ((short*)(ws + WS_WQST))[idx] = f2bf(SCALE * Wq_w[k * 256 + c]);
        return;
    }
    idx -= 32768;
    if (idx < 65536) {
        int c = idx >> 7, k = idx & 127;
        ((short*)(ws + WS_W2QT))[idx] = f2bf(ws[WS_W2Q + k * 512 + c]);
        return;
    }
    idx -= 65536;
    if (idx < 65536) {
        int c = idx >> 7, k = idx & 127;
        ((short*)(ws + WS_W2KT))[idx] = f2bf(ws[WS_W2K + k * 512 + c]);
        return;
    }
    idx -= 65536;
    if (idx < 32768) {
        int o = idx >> 8, c = idx & 255;
        ((short*)(ws + WS_WOT))[idx] = f2bf(Wo_w[c * 128 + o]);
        return;
    }
    idx -= 32768;
    if (idx < 256) { ws[WS_BQS + idx] = SCALE * Wq_b[idx]; return; }
    idx -= 256;
    if (idx < 65536) {
        int c = idx >> 7, k = idx & 127;
        ((short*)(ws + WS_WKVT))[idx] =
            f2bf(c < 256 ? Wk_w[k * 256 + c] : Wv_w[k * 256 + (c - 256)]);
        return;
    }
    idx -= 65536;
    if (idx < 512) ws[WS_BKV + idx] = (idx < 256) ? Wk_b[idx] : Wv_b[idx - 256];
}

__global__ void init_kernel(float* kmax) {
    if (threadIdx.x < 8) kmax[threadIdx.x] = -1e30f;
}

// ---------- kmax: 512 threads, wave = head, 64 rows/block ----------
__global__ __launch_bounds__(512, 4) void kmax_mfma_kernel(
    const float* __restrict__ x, const float* __restrict__ ws, float* __restrict__ kmax)
{
    __shared__ char smem[16384];
    const short* w2kt = (const short*)(ws + WS_W2KT);
    const float* b2k = ws + WS_B2K;
    const int t = threadIdx.x, w = t >> 6, l = t & 63, lg = l >> 4, li = l & 15;
    float b2r[4];
#pragma unroll
    for (int nc = 0; nc < 4; ++nc) b2r[nc] = b2k[w * 64 + nc * 16 + li];
    float mx = -1e30f;

    const int n0 = blockIdx.x * 64;
    {
        const int sr = t >> 3, sp = t & 7;
        float f[16];
        if (n0 + sr < NN) {
            const float* gp = x + (size_t)(n0 + sr) * 128 + sp * 16;
#pragma unroll
            for (int i = 0; i < 4; ++i) {
                float4 v = *(const float4*)(gp + i * 4);
                f[i*4] = v.x; f[i*4+1] = v.y; f[i*4+2] = v.z; f[i*4+3] = v.w;
            }
        } else {
#pragma unroll
            for (int i = 0; i < 16; ++i) f[i] = 0.f;
        }
        const int rb = sr * 256, sw = (sr & 7) << 4;
#pragma unroll
        for (int j = 0; j < 2; ++j) {
            short8 s;
#pragma unroll
            for (int e = 0; e < 8; ++e) s[e] = f2bf(f[j * 8 + e]);
            *(short8*)(smem + rb + ((sp * 32 + 16 * j) ^ sw)) = s;
        }
    }
    __syncthreads();
    short8 Bf[16];
#pragma unroll
    for (int kk = 0; kk < 4; ++kk)
#pragma unroll
        for (int nc = 0; nc < 4; ++nc)
            Bf[kk * 4 + nc] = *(const short8*)&w2kt[(w * 64 + nc * 16 + li) * 128 + kk * 32 + lg * 8];
#pragma unroll
    for (int mr = 0; mr < 4; ++mr) {
        f32x4 acc[4];
#pragma unroll
        for (int nc = 0; nc < 4; ++nc) acc[nc] = (f32x4){0.f, 0.f, 0.f, 0.f};
#pragma unroll
        for (int kk = 0; kk < 4; ++kk) {
            const int row = mr * 16 + li;
            const short8 a = *(const short8*)(smem + row * 256 + (((kk * 32 + lg * 8) * 2) ^ ((row & 7) << 4)));
#pragma unroll
            for (int nc = 0; nc < 4; ++nc) acc[nc] = MFMA16(a, Bf[kk * 4 + nc], acc[nc]);
        }
#pragma unroll
        for (int r = 0; r < 4; ++r) {
            if (n0 + mr * 16 + lg * 4 + r < NN) {
#pragma unroll
                for (int nc = 0; nc < 4; ++nc) mx = fmaxf(mx, acc[nc][r] + b2r[nc]);
            }
        }
    }
    mx = bmax16(mx); mx = fmaxf(mx, __shfl_xor(mx, 16)); mx = fmaxf(mx, __shfl_xor(mx, 32));
    if (l == 0) atomicMaxFloat(&kmax[w], mx);
}

// ---------- kvs: 512 threads, wave = head, 32 rows/tile, persistent ----------
// smem: [0,8192) xs [32][256B]; [8192,40960) kpT per-wave 4KB [64 m][64B];
//       [40960,57344) vT per-wave 2KB [32 d][64B]
__global__ __launch_bounds__(512, 4) void kvs_mfma_kernel(
    const float* __restrict__ x, const float* __restrict__ ws,
    float* __restrict__ partials, int nb)
{
    __shared__ char smem[57344];
    const short* wkvt = (const short*)(ws + WS_WKVT);
    const short* w2kt = (const short*)(ws + WS_W2KT);
    const float* bkv  = ws + WS_BKV;
    const float* b2k  = ws + WS_B2K;
    const float* kmaxp = ws + WS_KMAX;

    const int t = threadIdx.x, w = t >> 6, l = t & 63, lg = l >> 4, li = l & 15;
    char* kptb = smem + 8192 + w * 4096;
    char* vtb  = smem + 40960 + w * 2048;
    float bkv_r[4], b2_r[4];
#pragma unroll
    for (int nc = 0; nc < 4; ++nc) {
        bkv_r[nc] = (nc < 2) ? bkv[w * 32 + nc * 16 + li] : bkv[256 + w * 32 + (nc - 2) * 16 + li];
        b2_r[nc]  = b2k[w * 64 + nc * 16 + li];
    }
    const float km = kmaxp[w];

    f32x4 ak[4][2];
#pragma unroll
    for (int mr = 0; mr < 4; ++mr)
#pragma unroll
        for (int nc = 0; nc < 2; ++nc) ak[mr][nc] = (f32x4){0.f,0.f,0.f,0.f};
    float ksacc[4];
#pragma unroll
    for (int nc = 0; nc < 4; ++nc) ksacc[nc] = 0.f;

    for (int tile = blockIdx.x; tile < 3125; tile += nb) {
        const int n0 = tile * 32;
        __syncthreads();   // protect xs from previous tile's readers
        {
            const int sr = t >> 4, sp = t & 15;
            const float* gp = x + (size_t)(n0 + sr) * 128 + sp * 8;
            float f[8];
            float4 v0 = *(const float4*)gp, v1 = *(const float4*)(gp + 4);
            f[0]=v0.x; f[1]=v0.y; f[2]=v0.z; f[3]=v0.w;
            f[4]=v1.x; f[5]=v1.y; f[6]=v1.z; f[7]=v1.w;
            short8 s;
#pragma unroll
            for (int e = 0; e < 8; ++e) s[e] = f2bf(f[e]);
            *(short8*)(smem + sr * 256 + ((sp * 16) ^ ((sr & 7) << 4))) = s;
        }
        __syncthreads();
        float dgk[2][4];
        // ---- GEMM1: k (hf=0) then v (hf=1), 2 nc each ----
#pragma unroll
        for (int hf = 0; hf < 2; ++hf) {
            short8 Bf[8];
#pragma unroll
            for (int kk = 0; kk < 4; ++kk)
#pragma unroll
                for (int nc = 0; nc < 2; ++nc) {
                    const int brow = (hf == 0 ? w * 32 : 256 + w * 32) + nc * 16 + li;
                    Bf[kk * 2 + nc] = *(const short8*)&wkvt[brow * 128 + kk * 32 + lg * 8];
                }
            f32x4 acc[2][2];
#pragma unroll
            for (int mr = 0; mr < 2; ++mr)
#pragma unroll
                for (int nc = 0; nc < 2; ++nc) acc[mr][nc] = (f32x4){0.f,0.f,0.f,0.f};
#pragma unroll
            for (int kk = 0; kk < 4; ++kk)
#pragma unroll
                for (int mr = 0; mr < 2; ++mr) {
                    const int row = mr * 16 + li;
                    const short8 a = *(const short8*)(smem + row * 256 + (((kk * 32 + lg * 8) * 2) ^ ((row & 7) << 4)));
#pragma unroll
                    for (int nc = 0; nc < 2; ++nc) acc[mr][nc] = MFMA16(a, Bf[kk * 2 + nc], acc[mr][nc]);
                }
            if (hf == 0) {
#pragma unroll
                for (int mr = 0; mr < 2; ++mr)
#pragma unroll
                    for (int r = 0; r < 4; ++r) {
                        const float v0 = acc[mr][0][r] + bkv_r[0];
                        const float v1 = acc[mr][1][r] + bkv_r[1];
                        dgk[mr][r] = HALF_SCALE2 * bsum16(v0 * v0 + v1 * v1);
                    }
            } else {
#pragma unroll
                for (int mr = 0; mr < 2; ++mr)
#pragma unroll
                    for (int nc = 0; nc < 2; ++nc) {
                        short4 s4;
                        s4.x = f2bf(acc[mr][nc][0] + bkv_r[2 + nc]);
                        s4.y = f2bf(acc[mr][nc][1] + bkv_r[2 + nc]);
                        s4.z = f2bf(acc[mr][nc][2] + bkv_r[2 + nc]);
                        s4.w = f2bf(acc[mr][nc][3] + bkv_r[2 + nc]);
                        const int vrow = nc * 16 + li;
                        const int b = 32 * mr + 8 * lg;
                        *(short4*)(vtb + vrow * 64 +
                                   ((((b >> 4) ^ ((vrow >> 1) & 3)) << 4) | (b & 15))) = s4;
                    }
            }
        }
        // ---- GEMM2: kdash halves -> kp -> kpT (wave-private, no barrier) ----
#pragma unroll
        for (int hf = 0; hf < 2; ++hf) {
            short8 Bf[8];
#pragma unroll
            for (int kk = 0; kk < 4; ++kk)
#pragma unroll
                for (int nc = 0; nc < 2; ++nc)
                    Bf[kk * 2 + nc] = *(const short8*)&w2kt[(w * 64 + (hf * 2 + nc) * 16 + li) * 128 + kk * 32 + lg * 8];
            f32x4 acd[2][2];
#pragma unroll
            for (int mr = 0; mr < 2; ++mr)
#pragma unroll
                for (int nc = 0; nc < 2; ++nc) acd[mr][nc] = (f32x4){0.f,0.f,0.f,0.f};
#pragma unroll
            for (int kk = 0; kk < 4; ++kk)
#pragma unroll
                for (int mr = 0; mr < 2; ++mr) {
                    const int row = mr * 16 + li;
                    const short8 a = *(const short8*)(smem + row * 256 + (((kk * 32 + lg * 8) * 2) ^ ((row & 7) << 4)));
#pragma unroll
                    for (int nc = 0; nc < 2; ++nc) acd[mr][nc] = MFMA16(a, Bf[kk * 2 + nc], acd[mr][nc]);
                }
#pragma unroll
            for (int mr = 0; mr < 2; ++mr)
#pragma unroll
                for (int nc = 0; nc < 2; ++nc) {
                    short4 s4;
#pragma unroll
                    for (int r = 0; r < 4; ++r) {
                        const float val = acd[mr][nc][r] + b2_r[hf * 2 + nc];
                        const float kp = RATIO * (__expf(val - dgk[mr][r] - km) + KEPS);
                        const short sb = f2bf(kp);
                        ksacc[hf * 2 + nc] += bf2f(sb);
                        if (r == 0) s4.x = sb; else if (r == 1) s4.y = sb;
                        else if (r == 2) s4.z = sb; else s4.w = sb;
                    }
                    const int mrow = (hf * 2 + nc) * 16 + li;
                    const int b = 32 * mr + 8 * lg;
                    *(short4*)(kptb + mrow * 64 +
                               ((((b >> 4) ^ ((mrow >> 1) & 3)) << 4) | (b & 15))) = s4;
                }
        }
        // ---- GEMM3: kvs += kpT @ v (wave-private LDS) ----
        {
            short8 aa[4], bv[2];
#pragma unroll
            for (int mr = 0; mr < 4; ++mr) {
                const int row = mr * 16 + li;
                aa[mr] = *(const short8*)(kptb + row * 64 + ((lg ^ ((row >> 1) & 3)) << 4));
            }
#pragma unroll
            for (int nc = 0; nc < 2; ++nc) {
                const int vrow = nc * 16 + li;
                bv[nc] = *(const short8*)(vtb + vrow * 64 + ((lg ^ ((vrow >> 1) & 3)) << 4));
            }
#pragma unroll
            for (int mr = 0; mr < 4; ++mr)
#pragma unroll
                for (int nc = 0; nc < 2; ++nc)
                    ak[mr][nc] = MFMA16(aa[mr], bv[nc], ak[mr][nc]);
        }
    }
    float* pb = partials + (size_t)blockIdx.x * 16896;
#pragma unroll
    for (int mr = 0; mr < 4; ++mr)
#pragma unroll
        for (int nc = 0; nc < 2; ++nc)
#pragma unroll
            for (int r = 0; r < 4; ++r) {
                const int m = mr * 16 + lg * 4 + r;
                const int d = nc * 16 + li;
                pb[(w * 64 + m) * 32 + d] = ak[mr][nc][r];
            }
#pragma unroll
    for (int nc = 0; nc < 4; ++nc) {
        float s = ksacc[nc];
        s += __shfl_xor(s, 16); s += __shfl_xor(s, 32);
        if (lg == 0) pb[16384 + w * 64 + nc * 16 + li] = s;
    }
}

// ---------- two-stage deterministic reduce ----------
__global__ __launch_bounds__(256) void reduce1_kernel(
    const float* __restrict__ partials, float* __restrict__ red2, int nb)
{
    const int b = blockIdx.x;
    const int part = b & 7, grp = b >> 3;
    const int idx = grp * 256 + threadIdx.x;
    if (idx >= 16896) return;
    const int per = (nb + 7) >> 3;
    const int lo = part * per;
    const int hi = (lo + per < nb) ? (lo + per) : nb;
    float s = 0.f;
    for (int q = lo; q < hi; ++q) s += partials[(size_t)q * 16896 + idx];
    red2[part * 16896 + idx] = s;
}

__global__ __launch_bounds__(256) void reduce2_kernel(
    const float* __restrict__ red2, float* __restrict__ ws)
{
    const int idx = blockIdx.x * 256 + threadIdx.x;
    if (idx >= 16896) return;
    float s = 0.f;
#pragma unroll
    for (int p = 0; p < 8; ++p) s += red2[p * 16896 + idx];
    ws[WS_KVSKS + idx] = s;
    if (idx < 16384) {
        const int h = idx >> 11, m = (idx >> 5) & 63, d = idx & 31;
        ((short*)(ws + WS_KVST))[(h * 32 + d) * 64 + m] = f2bf(s);
    }
}

// ---------- out: 512 threads, wave = head, 64 rows/block ----------
// smem: [0,16384) xs [64][256B]; [16384,49152) zs [64][512B]; [49152,65536) qp per-wave 2KB
__global__ __launch_bounds__(512, 4) void out_mfma_kernel(
    const float* __restrict__ x, const float* __restrict__ ws,
    const float* __restrict__ alpha, const float* __restrict__ beta,
    const float* __restrict__ Wo_b, float* __restrict__ out)
{
    __shared__ char smem[65536];
    const short* wqst = (const short*)(ws + WS_WQST);
    const short* w2qt = (const short*)(ws + WS_W2QT);
    const short* wot  = (const short*)(ws + WS_WOT);
    const short* kvst = (const short*)(ws + WS_KVST);
    const float* bqs  = ws + WS_BQS;
    const float* b2q  = ws + WS_B2Q;
    const float* ksum = ws + WS_KVSKS + 16384;

    const int t = threadIdx.x, w = t >> 6, l = t & 63, lg = l >> 4, li = l & 15;
    const float a_ = __expf(alpha[0]), b_ = __expf(beta[0]);
    const float a2 = a_ * a_, bc = b_ * (a_ + 1.f);
    char* qpb = smem + 49152 + w * 2048;

    float bq_r[2], b2_r[4], ksv[4];
#pragma unroll
    for (int nc = 0; nc < 2; ++nc) bq_r[nc] = bqs[w * 32 + nc * 16 + li];
#pragma unroll
    for (int nc = 0; nc < 4; ++nc) {
        b2_r[nc] = b2q[w * 64 + nc * 16 + li];
        ksv[nc]  = ksum[w * 64 + nc * 16 + li];
    }
    const float bo = Wo_b[w * 16 + li];

    const int n0 = blockIdx.x * 64;
    {
        const int sr = t >> 3, sp = t & 7;
        float f[16];
        if (n0 + sr < NN) {
            const float* gp = x + (size_t)(n0 + sr) * 128 + sp * 16;
#pragma unroll
            for (int i = 0; i < 4; ++i) {
                float4 v = *(const float4*)(gp + i * 4);
                f[i*4] = v.x; f[i*4+1] = v.y; f[i*4+2] = v.z; f[i*4+3] = v.w;
            }
        } else {
#pragma unroll
            for (int i = 0; i < 16; ++i) f[i] = 0.f;
        }
        const int rb = sr * 256, sw = (sr & 7) << 4;
#pragma unroll
        for (int j = 0; j < 2; ++j) {
            short8 s;
#pragma unroll
            for (int e = 0; e < 8; ++e) s[e] = f2bf(f[j * 8 + e]);
            *(short8*)(smem + rb + ((sp * 32 + 16 * j) ^ sw)) = s;
        }
    }
    __syncthreads();
    // ---- Q phase: diag (registers) ----
    float dg[4][4];
    {
        short8 Bq[8];
#pragma unroll
        for (int kk = 0; kk < 4; ++kk)
#pragma unroll
            for (int nc = 0; nc < 2; ++nc)
                Bq[kk * 2 + nc] = *(const short8*)&wqst[(w * 32 + nc * 16 + li) * 128 + kk * 32 + lg * 8];
#pragma unroll
        for (int mr = 0; mr < 4; ++mr) {
            f32x4 aq[2];
#pragma unroll
            for (int nc = 0; nc < 2; ++nc) aq[nc] = (f32x4){0.f,0.f,0.f,0.f};
#pragma unroll
            for (int kk = 0; kk < 4; ++kk) {
                const int row = mr * 16 + li;
                const short8 a = *(const short8*)(smem + row * 256 + (((kk * 32 + lg * 8) * 2) ^ ((row & 7) << 4)));
#pragma unroll
                for (int nc = 0; nc < 2; ++nc) aq[nc] = MFMA16(a, Bq[kk * 2 + nc], aq[nc]);
            }
#pragma unroll
            for (int r = 0; r < 4; ++r) {
                const float v0 = aq[0][r] + bq_r[0], v1 = aq[1][r] + bq_r[1];
                dg[mr][r] = 0.5f * bsum16(v0 * v0 + v1 * v1);
            }
        }
    }
    // ---- Kf hoist ----
    short8 Kf[4];
#pragma unroll
    for (int kk = 0; kk < 2; ++kk)
#pragma unroll
        for (int nc = 0; nc < 2; ++nc)
            Kf[kk * 2 + nc] = *(const short8*)&kvst[(w * 32 + nc * 16 + li) * 64 + kk * 32 + lg * 8];
    // ---- QD + softmax + Z per mr ----
#pragma unroll
    for (int mr = 0; mr < 4; ++mr) {
        f32x4 ad[4];
#pragma unroll
        for (int hf = 0; hf < 2; ++hf) {
            short8 Bf[8];
#pragma unroll
            for (int kk = 0; kk < 4; ++kk)
#pragma unroll
                for (int nc = 0; nc < 2; ++nc)
                    Bf[kk * 2 + nc] = *(const short8*)&w2qt[(w * 64 + (hf * 2 + nc) * 16 + li) * 128 + kk * 32 + lg * 8];
            f32x4 a0 = (f32x4){0.f,0.f,0.f,0.f}, a1 = (f32x4){0.f,0.f,0.f,0.f};
#pragma unroll
            for (int kk = 0; kk < 4; ++kk) {
                const int row = mr * 16 + li;
                const short8 a = *(const short8*)(smem + row * 256 + (((kk * 32 + lg * 8) * 2) ^ ((row & 7) << 4)));
                a0 = MFMA16(a, Bf[kk * 2 + 0], a0);
                a1 = MFMA16(a, Bf[kk * 2 + 1], a1);
            }
            ad[hf * 2 + 0] = a0; ad[hf * 2 + 1] = a1;
        }
        float zd[4];
#pragma unroll
        for (int r = 0; r < 4; ++r) {
            float vv[4];
#pragma unroll
            for (int nc = 0; nc < 4; ++nc) vv[nc] = ad[nc][r] + b2_r[nc];
            float mx = fmaxf(fmaxf(vv[0], vv[1]), fmaxf(vv[2], vv[3]));
            mx = bmax16(mx);
            const int rr = lg * 4 + r;
            float z = 0.f;
#pragma unroll
            for (int nc = 0; nc < 4; ++nc) {
                const float e = RATIO * (__expf(vv[nc] - dg[mr][r] - mx) + KEPS);
                z = fmaf(e, ksv[nc], z);
                const unsigned pe = (unsigned)(unsigned short)f2bf(e);
                const unsigned po = (unsigned)__shfl_xor((int)pe, 1);
                if (!(li & 1))
                    *(unsigned*)(qpb + rr * 128 +
                        ((nc * 32 + 2 * li) ^ ((rr & 7) << 4))) = pe | (po << 16);
            }
            zd[r] = bsum16(z);
        }
        f32x4 az[2];
#pragma unroll
        for (int nc = 0; nc < 2; ++nc) az[nc] = (f32x4){0.f,0.f,0.f,0.f};
#pragma unroll
        for (int kk = 0; kk < 2; ++kk) {
            const short8 aa = *(const short8*)(qpb + li * 128 +
                              ((kk * 64 + lg * 16) ^ ((li & 7) << 4)));
#pragma unroll
            for (int nc = 0; nc < 2; ++nc) az[nc] = MFMA16(aa, Kf[kk * 2 + nc], az[nc]);
        }
#pragma unroll
        for (int nc = 0; nc < 2; ++nc)
#pragma unroll
            for (int r = 0; r < 4; ++r) {
                const int row = mr * 16 + lg * 4 + r;
                const float zv = az[nc][r] / zd[r];
                const unsigned pe = (unsigned)(unsigned short)f2bf(zv);
                const unsigned po = (unsigned)__shfl_xor((int)pe, 1);
                if (!(li & 1))
                    *(unsigned*)(smem + 16384 + row * 512 +
                        ((2 * (w * 32 + nc * 16 + li)) ^ ((row & 7) << 4))) = pe | (po << 16);
            }
    }
    // ---- O weights issued before barrier ----
    short8 Bo[8];
#pragma unroll
    for (int kk = 0; kk < 8; ++kk)
        Bo[kk] = *(const short8*)&wot[(w * 16 + li) * 256 + kk * 32 + lg * 8];
    __syncthreads();   // zs complete
    f32x4 ao[4];
#pragma unroll
    for (int mr = 0; mr < 4; ++mr) ao[mr] = (f32x4){0.f,0.f,0.f,0.f};
#pragma unroll
    for (int mr = 0; mr < 4; ++mr)
#pragma unroll
        for (int kk = 0; kk < 8; ++kk) {
            const int row = mr * 16 + li;
            const short8 aa = *(const short8*)(smem + 16384 + row * 512 +
                              ((kk * 64 + lg * 16) ^ ((row & 7) << 4)));
            ao[mr] = MFMA16(aa, Bo[kk], ao[mr]);
        }
#pragma unroll
    for (int mr = 0; mr < 4; ++mr)
#pragma unroll
        for (int r = 0; r < 4; ++r) {
            const int n = n0 + mr * 16 + lg * 4 + r;
            if (n < NN) {
                const int c = w * 16 + li;
                const float xn = ao[mr][r] + bo;
                out[(size_t)n * 128 + c] = a2 * x[(size_t)n * 128 + c] + bc * xn;
            }
        }
}

extern "C" void kernel_launch(void* const* d_in, const int* in_sizes, int n_in,
                              void* d_out, int out_size, void* d_ws, size_t ws_size,
                              hipStream_t stream) {
    (void)in_sizes; (void)n_in; (void)out_size;
    const float* x    = (const float*)d_in[0];
    const float* Wq_w = (const float*)d_in[2];
    const float* Wq_b = (const float*)d_in[3];
    const float* Wk_w = (const float*)d_in[4];
    const float* Wk_b = (const float*)d_in[5];
    const float* Wv_w = (const float*)d_in[6];
    const float* Wv_b = (const float*)d_in[7];
    const float* Wo_w = (const float*)d_in[8];
    const float* Wo_b = (const float*)d_in[9];
    const float* alpha= (const float*)d_in[10];
    const float* beta = (const float*)d_in[11];
    const float* proj = (const float*)d_in[12];
    float* out = (float*)d_out;
    float* ws  = (float*)d_ws;

    float* kmax     = ws + WS_KMAX;
    float* red2     = ws + WS_RED2;
    float* partials = ws + WS_PART;
    const size_t availf = (ws_size / 4 > (size_t)WS_PART) ? (ws_size / 4 - WS_PART) : 0;
    int nb = (int)(availf / 16896);
    if (nb > 625) nb = 625;
    if (nb < 1) nb = 1;

    init_kernel<<<1, 64, 0, stream>>>(kmax);
    fold_kernel<<<258, 256, 0, stream>>>(Wq_w, Wq_b, proj, ws + WS_W2Q, ws + WS_B2Q);
    fold_kernel<<<258, 256, 0, stream>>>(Wk_w, Wk_b, proj, ws + WS_W2K, ws + WS_B2K);
    prep_kernel<<<1027, 256, 0, stream>>>(Wq_w, Wq_b, Wk_w, Wk_b, Wv_w, Wv_b, Wo_w, ws);
    kmax_mfma_kernel<<<1563, 512, 0, stream>>>(x, ws, kmax);
    kvs_mfma_kernel<<<nb, 512, 0, stream>>>(x, ws, partials, nb);
    reduce1_kernel<<<528, 256, 0, stream>>>(partials, red2, nb);
    reduce2_kernel<<<66, 256, 0, stream>>>(red2, ws);
    out_mfma_kernel<<<1563, 512, 0, stream>>>(x, ws, alpha, beta, Wo_b, out);
}

// Round 7
// 578.928 us; speedup vs baseline: 1.4322x; 1.0349x over previous
//
#include <hip/hip_runtime.h>
#include <math.h>

#define NN 100000
#define SCALE 0.8408964152537145f  // inv_sqrt_tau(=2) * 32^-0.25
#define HALF_SCALE2 0.3535533905932738f // 0.5 * SCALE^2
#define RATIO 0.125f               // 64^-0.5
#define KEPS 1e-6f

// ws layout (float offsets)
#define WS_KMAX 0
#define WS_KVSKS 8          // 16384 kvs fp32 + 512 ks fp32
#define WS_KVST 16904       // kvsT bf16 [8][32][64] -> 8192 floats
#define WS_W2Q 25096        // fp32 [128][512]
#define WS_W2K 90632        // fp32 [128][512]
#define WS_B2Q 156168       // 512
#define WS_B2K 156680       // 512
#define WS_W2QT 157192      // bf16 [512][128] -> 32768 floats
#define WS_W2KT 189960      // bf16 [512][128]
#define WS_WQST 222728      // bf16 [256][128] (SCALE*Wq)^T -> 16384 floats
#define WS_WOT 239112       // bf16 [128][256] Wo^T -> 16384 floats
#define WS_BQS 255496       // 256 fp32 (SCALE*Wq_b)
#define WS_WKVT 255752      // bf16 [512][128] [Wk|Wv]^T -> 32768 floats
#define WS_BKV 288520       // 512 fp32 [bk|bv]
#define WS_RED2 289032      // 8*16896 fp32 stage-2 reduce partials
#define WS_PART 424200      // nb * 16896

typedef __attribute__((ext_vector_type(8))) short short8;
typedef __attribute__((ext_vector_type(4))) float f32x4;

#define MFMA16(a, b, c) __builtin_amdgcn_mfma_f32_16x16x32_bf16((a), (b), (c), 0, 0, 0)

__device__ __forceinline__ short f2bf(float f) {
    union { float f; unsigned u; } a; a.f = f;
    unsigned r = a.u + 0x7fffu + ((a.u >> 16) & 1u);
    return (short)(r >> 16);
}
__device__ __forceinline__ float bf2f(short s) {
    union { float f; unsigned u; } a; a.u = ((unsigned)(unsigned short)s) << 16;
    return a.f;
}

__device__ __forceinline__ float bsum16(float v) {
    v += __shfl_xor(v, 1); v += __shfl_xor(v, 2);
    v += __shfl_xor(v, 4); v += __shfl_xor(v, 8);
    return v;
}
__device__ __forceinline__ float bmax16(float v) {
    v = fmaxf(v, __shfl_xor(v, 1)); v = fmaxf(v, __shfl_xor(v, 2));
    v = fmaxf(v, __shfl_xor(v, 4)); v = fmaxf(v, __shfl_xor(v, 8));
    return v;
}

__device__ __forceinline__ void atomicMaxFloat(float* addr, float val) {
    int* ai = (int*)addr;
    int cur = *((volatile int*)ai);
    while (val > __int_as_float(cur)) {
        int assumed = cur;
        cur = atomicCAS(ai, assumed, __float_as_int(val));
        if (cur == assumed) break;
    }
}

// ---------- fold ----------
__global__ __launch_bounds__(256) void fold_kernel(
    const float* __restrict__ W, const float* __restrict__ b,
    const float* __restrict__ proj,
    float* __restrict__ W2, float* __restrict__ b2)
{
    const int idx = blockIdx.x * 256 + threadIdx.x;
    if (idx >= 129 * 512) return;
    const int row = idx >> 9;
    const int col = idx & 511;
    const int h = col >> 6, m = col & 63;
    const float* src = (row < 128) ? (W + row * 256 + h * 32) : (b + h * 32);
    float s = 0.f;
#pragma unroll
    for (int d = 0; d < 32; ++d) s = fmaf(src[d], proj[m * 32 + d], s);
    s *= SCALE;
    if (row < 128) W2[row * 512 + col] = s;
    else           b2[col] = s;
}

// ---------- prep ----------
__global__ __launch_bounds__(256) void prep_kernel(
    const float* __restrict__ Wq_w, const float* __restrict__ Wq_b,
    const float* __restrict__ Wk_w, const float* __restrict__ Wk_b,
    const float* __restrict__ Wv_w, const float* __restrict__ Wv_b,
    const float* __restrict__ Wo_w, float* __restrict__ ws)
{
    int idx = blockIdx.x * 256 + threadIdx.x;
    if (idx < 32768) {
        int c = idx >> 7, k = idx & 127;
        ((short*)(ws + WS_WQST))[idx] = f2bf(SCALE * Wq_w[k * 256 + c]);
        return;
    }
    idx -= 32768;
    if (idx < 65536) {
        int c = idx >> 7, k = idx & 127;
        ((short*)(ws + WS_W2QT))[idx] = f2bf(ws[WS_W2Q + k * 512 + c]);
        return;
    }
    idx -= 65536;
    if (idx < 65536) {
        int c = idx >> 7, k = idx & 127;
        ((short*)(ws + WS_W2KT))[idx] = f2bf(ws[WS_W2K + k * 512 + c]);
        return;
    }
    idx -= 65536;
    if (idx < 32768) {
        int o = idx >> 8, c = idx & 255;
        ((short*)(ws + WS_WOT))[idx] = f2bf(Wo_w[c * 128 + o]);
        return;
    }
    idx -= 32768;
    if (idx < 256) { ws[WS_BQS + idx] = SCALE * Wq_b[idx]; return; }
    idx -= 256;
    if (idx < 65536) {
        int c = idx >> 7, k = idx & 127;
        ((short*)(ws + WS_WKVT))[idx] =
            f2bf(c < 256 ? Wk_w[k * 256 + c] : Wv_w[k * 256 + (c - 256)]);
        return;
    }
    idx -= 65536;
    if (idx < 512) ws[WS_BKV + idx] = (idx < 256) ? Wk_b[idx] : Wv_b[idx - 256];
}

__global__ void init_kernel(float* kmax) {
    if (threadIdx.x < 8) kmax[threadIdx.x] = -1e30f;
}

// ---------- kmax: 512 threads, wave = head, 64 rows/block ----------
__global__ __launch_bounds__(512, 4) void kmax_mfma_kernel(
    const float* __restrict__ x, const float* __restrict__ ws, float* __restrict__ kmax)
{
    __shared__ char smem[16384];
    const short* w2kt = (const short*)(ws + WS_W2KT);
    const float* b2k = ws + WS_B2K;
    const int t = threadIdx.x, w = t >> 6, l = t & 63, lg = l >> 4, li = l & 15;
    float b2r[4];
#pragma unroll
    for (int nc = 0; nc < 4; ++nc) b2r[nc] = b2k[w * 64 + nc * 16 + li];
    float mx = -1e30f;

    const int n0 = blockIdx.x * 64;
    {
        const int sr = t >> 3, sp = t & 7;
        float f[16];
        if (n0 + sr < NN) {
            const float* gp = x + (size_t)(n0 + sr) * 128 + sp * 16;
#pragma unroll
            for (int i = 0; i < 4; ++i) {
                float4 v = *(const float4*)(gp + i * 4);
                f[i*4] = v.x; f[i*4+1] = v.y; f[i*4+2] = v.z; f[i*4+3] = v.w;
            }
        } else {
#pragma unroll
            for (int i = 0; i < 16; ++i) f[i] = 0.f;
        }
        const int rb = sr * 256, sw = (sr & 7) << 4;
#pragma unroll
        for (int j = 0; j < 2; ++j) {
            short8 s;
#pragma unroll
            for (int e = 0; e < 8; ++e) s[e] = f2bf(f[j * 8 + e]);
            *(short8*)(smem + rb + ((sp * 32 + 16 * j) ^ sw)) = s;
        }
    }
    __syncthreads();
    short8 Bf[16];
#pragma unroll
    for (int kk = 0; kk < 4; ++kk)
#pragma unroll
        for (int nc = 0; nc < 4; ++nc)
            Bf[kk * 4 + nc] = *(const short8*)&w2kt[(w * 64 + nc * 16 + li) * 128 + kk * 32 + lg * 8];
#pragma unroll
    for (int mr = 0; mr < 4; ++mr) {
        f32x4 acc[4];
#pragma unroll
        for (int nc = 0; nc < 4; ++nc) acc[nc] = (f32x4){0.f, 0.f, 0.f, 0.f};
#pragma unroll
        for (int kk = 0; kk < 4; ++kk) {
            const int row = mr * 16 + li;
            const short8 a = *(const short8*)(smem + row * 256 + (((kk * 32 + lg * 8) * 2) ^ ((row & 7) << 4)));
#pragma unroll
            for (int nc = 0; nc < 4; ++nc) acc[nc] = MFMA16(a, Bf[kk * 4 + nc], acc[nc]);
        }
#pragma unroll
        for (int r = 0; r < 4; ++r) {
            if (n0 + mr * 16 + lg * 4 + r < NN) {
#pragma unroll
                for (int nc = 0; nc < 4; ++nc) mx = fmaxf(mx, acc[nc][r] + b2r[nc]);
            }
        }
    }
    mx = bmax16(mx); mx = fmaxf(mx, __shfl_xor(mx, 16)); mx = fmaxf(mx, __shfl_xor(mx, 32));
    if (l == 0) atomicMaxFloat(&kmax[w], mx);
}

// ---------- kvs: 512 threads, wave = head, 32 rows/tile, persistent ----------
__global__ __launch_bounds__(512, 4) void kvs_mfma_kernel(
    const float* __restrict__ x, const float* __restrict__ ws,
    float* __restrict__ partials, int nb)
{
    __shared__ char smem[57344];
    const short* wkvt = (const short*)(ws + WS_WKVT);
    const short* w2kt = (const short*)(ws + WS_W2KT);
    const float* bkv  = ws + WS_BKV;
    const float* b2k  = ws + WS_B2K;
    const float* kmaxp = ws + WS_KMAX;

    const int t = threadIdx.x, w = t >> 6, l = t & 63, lg = l >> 4, li = l & 15;
    char* kptb = smem + 8192 + w * 4096;
    char* vtb  = smem + 40960 + w * 2048;
    float bkv_r[4], b2_r[4];
#pragma unroll
    for (int nc = 0; nc < 4; ++nc) {
        bkv_r[nc] = (nc < 2) ? bkv[w * 32 + nc * 16 + li] : bkv[256 + w * 32 + (nc - 2) * 16 + li];
        b2_r[nc]  = b2k[w * 64 + nc * 16 + li];
    }
    const float km = kmaxp[w];

    f32x4 ak[4][2];
#pragma unroll
    for (int mr = 0; mr < 4; ++mr)
#pragma unroll
        for (int nc = 0; nc < 2; ++nc) ak[mr][nc] = (f32x4){0.f,0.f,0.f,0.f};
    float ksacc[4];
#pragma unroll
    for (int nc = 0; nc < 4; ++nc) ksacc[nc] = 0.f;

    for (int tile = blockIdx.x; tile < 3125; tile += nb) {
        const int n0 = tile * 32;
        __syncthreads();
        {
            const int sr = t >> 4, sp = t & 15;
            const float* gp = x + (size_t)(n0 + sr) * 128 + sp * 8;
            float f[8];
            float4 v0 = *(const float4*)gp, v1 = *(const float4*)(gp + 4);
            f[0]=v0.x; f[1]=v0.y; f[2]=v0.z; f[3]=v0.w;
            f[4]=v1.x; f[5]=v1.y; f[6]=v1.z; f[7]=v1.w;
            short8 s;
#pragma unroll
            for (int e = 0; e < 8; ++e) s[e] = f2bf(f[e]);
            *(short8*)(smem + sr * 256 + ((sp * 16) ^ ((sr & 7) << 4))) = s;
        }
        __syncthreads();
        float dgk[2][4];
#pragma unroll
        for (int hf = 0; hf < 2; ++hf) {
            short8 Bf[8];
#pragma unroll
            for (int kk = 0; kk < 4; ++kk)
#pragma unroll
                for (int nc = 0; nc < 2; ++nc) {
                    const int brow = (hf == 0 ? w * 32 : 256 + w * 32) + nc * 16 + li;
                    Bf[kk * 2 + nc] = *(const short8*)&wkvt[brow * 128 + kk * 32 + lg * 8];
                }
            f32x4 acc[2][2];
#pragma unroll
            for (int mr = 0; mr < 2; ++mr)
#pragma unroll
                for (int nc = 0; nc < 2; ++nc) acc[mr][nc] = (f32x4){0.f,0.f,0.f,0.f};
#pragma unroll
            for (int kk = 0; kk < 4; ++kk)
#pragma unroll
                for (int mr = 0; mr < 2; ++mr) {
                    const int row = mr * 16 + li;
                    const short8 a = *(const short8*)(smem + row * 256 + (((kk * 32 + lg * 8) * 2) ^ ((row & 7) << 4)));
#pragma unroll
                    for (int nc = 0; nc < 2; ++nc) acc[mr][nc] = MFMA16(a, Bf[kk * 2 + nc], acc[mr][nc]);
                }
            if (hf == 0) {
#pragma unroll
                for (int mr = 0; mr < 2; ++mr)
#pragma unroll
                    for (int r = 0; r < 4; ++r) {
                        const float v0 = acc[mr][0][r] + bkv_r[0];
                        const float v1 = acc[mr][1][r] + bkv_r[1];
                        dgk[mr][r] = HALF_SCALE2 * bsum16(v0 * v0 + v1 * v1);
                    }
            } else {
#pragma unroll
                for (int mr = 0; mr < 2; ++mr)
#pragma unroll
                    for (int nc = 0; nc < 2; ++nc) {
                        short4 s4;
                        s4.x = f2bf(acc[mr][nc][0] + bkv_r[2 + nc]);
                        s4.y = f2bf(acc[mr][nc][1] + bkv_r[2 + nc]);
                        s4.z = f2bf(acc[mr][nc][2] + bkv_r[2 + nc]);
                        s4.w = f2bf(acc[mr][nc][3] + bkv_r[2 + nc]);
                        const int vrow = nc * 16 + li;
                        const int b = 32 * mr + 8 * lg;
                        *(short4*)(vtb + vrow * 64 +
                                   ((((b >> 4) ^ ((vrow >> 1) & 3)) << 4) | (b & 15))) = s4;
                    }
            }
        }
#pragma unroll
        for (int hf = 0; hf < 2; ++hf) {
            short8 Bf[8];
#pragma unroll
            for (int kk = 0; kk < 4; ++kk)
#pragma unroll
                for (int nc = 0; nc < 2; ++nc)
                    Bf[kk * 2 + nc] = *(const short8*)&w2kt[(w * 64 + (hf * 2 + nc) * 16 + li) * 128 + kk * 32 + lg * 8];
            f32x4 acd[2][2];
#pragma unroll
            for (int mr = 0; mr < 2; ++mr)
#pragma unroll
                for (int nc = 0; nc < 2; ++nc) acd[mr][nc] = (f32x4){0.f,0.f,0.f,0.f};
#pragma unroll
            for (int kk = 0; kk < 4; ++kk)
#pragma unroll
                for (int mr = 0; mr < 2; ++mr) {
                    const int row = mr * 16 + li;
                    const short8 a = *(const short8*)(smem + row * 256 + (((kk * 32 + lg * 8) * 2) ^ ((row & 7) << 4)));
#pragma unroll
                    for (int nc = 0; nc < 2; ++nc) acd[mr][nc] = MFMA16(a, Bf[kk * 2 + nc], acd[mr][nc]);
                }
#pragma unroll
            for (int mr = 0; mr < 2; ++mr)
#pragma unroll
                for (int nc = 0; nc < 2; ++nc) {
                    short4 s4;
#pragma unroll
                    for (int r = 0; r < 4; ++r) {
                        const float val = acd[mr][nc][r] + b2_r[hf * 2 + nc];
                        const float kp = RATIO * (__expf(val - dgk[mr][r] - km) + KEPS);
                        const short sb = f2bf(kp);
                        ksacc[hf * 2 + nc] += bf2f(sb);
                        if (r == 0) s4.x = sb; else if (r == 1) s4.y = sb;
                        else if (r == 2) s4.z = sb; else s4.w = sb;
                    }
                    const int mrow = (hf * 2 + nc) * 16 + li;
                    const int b = 32 * mr + 8 * lg;
                    *(short4*)(kptb + mrow * 64 +
                               ((((b >> 4) ^ ((mrow >> 1) & 3)) << 4) | (b & 15))) = s4;
                }
        }
        {
            short8 aa[4], bv[2];
#pragma unroll
            for (int mr = 0; mr < 4; ++mr) {
                const int row = mr * 16 + li;
                aa[mr] = *(const short8*)(kptb + row * 64 + ((lg ^ ((row >> 1) & 3)) << 4));
            }
#pragma unroll
            for (int nc = 0; nc < 2; ++nc) {
                const int vrow = nc * 16 + li;
                bv[nc] = *(const short8*)(vtb + vrow * 64 + ((lg ^ ((vrow >> 1) & 3)) << 4));
            }
#pragma unroll
            for (int mr = 0; mr < 4; ++mr)
#pragma unroll
                for (int nc = 0; nc < 2; ++nc)
                    ak[mr][nc] = MFMA16(aa[mr], bv[nc], ak[mr][nc]);
        }
    }
    float* pb = partials + (size_t)blockIdx.x * 16896;
#pragma unroll
    for (int mr = 0; mr < 4; ++mr)
#pragma unroll
        for (int nc = 0; nc < 2; ++nc)
#pragma unroll
            for (int r = 0; r < 4; ++r) {
                const int m = mr * 16 + lg * 4 + r;
                const int d = nc * 16 + li;
                pb[(w * 64 + m) * 32 + d] = ak[mr][nc][r];
            }
#pragma unroll
    for (int nc = 0; nc < 4; ++nc) {
        float s = ksacc[nc];
        s += __shfl_xor(s, 16); s += __shfl_xor(s, 32);
        if (lg == 0) pb[16384 + w * 64 + nc * 16 + li] = s;
    }
}

// ---------- two-stage deterministic reduce ----------
__global__ __launch_bounds__(256) void reduce1_kernel(
    const float* __restrict__ partials, float* __restrict__ red2, int nb)
{
    const int b = blockIdx.x;
    const int part = b & 7, grp = b >> 3;
    const int idx = grp * 256 + threadIdx.x;
    if (idx >= 16896) return;
    const int per = (nb + 7) >> 3;
    const int lo = part * per;
    const int hi = (lo + per < nb) ? (lo + per) : nb;
    float s = 0.f;
    for (int q = lo; q < hi; ++q) s += partials[(size_t)q * 16896 + idx];
    red2[part * 16896 + idx] = s;
}

__global__ __launch_bounds__(256) void reduce2_kernel(
    const float* __restrict__ red2, float* __restrict__ ws)
{
    const int idx = blockIdx.x * 256 + threadIdx.x;
    if (idx >= 16896) return;
    float s = 0.f;
#pragma unroll
    for (int p = 0; p < 8; ++p) s += red2[p * 16896 + idx];
    ws[WS_KVSKS + idx] = s;
    if (idx < 16384) {
        const int h = idx >> 11, m = (idx >> 5) & 63, d = idx & 31;
        ((short*)(ws + WS_KVST))[(h * 32 + d) * 64 + m] = f2bf(s);
    }
}

// ---------- out: 512 threads, wave = head, 64 rows/block ----------
// smem: [0,16384) xs [64][256B]; [16384,49152) zs [64][512B] (later xn fp32 [64][132]);
//       [49152,65536) qp per-wave 2KB
__global__ __launch_bounds__(512, 4) void out_mfma_kernel(
    const float* __restrict__ x, const float* __restrict__ ws,
    const float* __restrict__ alpha, const float* __restrict__ beta,
    const float* __restrict__ Wo_b, float* __restrict__ out)
{
    __shared__ char smem[65536];
    const short* wqst = (const short*)(ws + WS_WQST);
    const short* w2qt = (const short*)(ws + WS_W2QT);
    const short* wot  = (const short*)(ws + WS_WOT);
    const short* kvst = (const short*)(ws + WS_KVST);
    const float* bqs  = ws + WS_BQS;
    const float* b2q  = ws + WS_B2Q;
    const float* ksum = ws + WS_KVSKS + 16384;

    const int t = threadIdx.x, w = t >> 6, l = t & 63, lg = l >> 4, li = l & 15;
    const float a_ = __expf(alpha[0]), b_ = __expf(beta[0]);
    const float a2 = a_ * a_, bc = b_ * (a_ + 1.f);
    char* qpb = smem + 49152 + w * 2048;

    float bq_r[2], b2_r[4], ksv[4];
#pragma unroll
    for (int nc = 0; nc < 2; ++nc) bq_r[nc] = bqs[w * 32 + nc * 16 + li];
#pragma unroll
    for (int nc = 0; nc < 4; ++nc) {
        b2_r[nc] = b2q[w * 64 + nc * 16 + li];
        ksv[nc]  = ksum[w * 64 + nc * 16 + li];
    }
    const float bo = Wo_b[w * 16 + li];

    const int n0 = blockIdx.x * 64;
    // ---- x -> registers (once) + bf16 swizzled LDS stage ----
    float4 xr[4];
    {
        const int c4 = (t & 31) * 4;
#pragma unroll
        for (int i = 0; i < 4; ++i) {
            const int sr = (t >> 5) + i * 16;
            if (n0 + sr < NN) xr[i] = *(const float4*)(x + (size_t)(n0 + sr) * 128 + c4);
            else xr[i] = make_float4(0.f, 0.f, 0.f, 0.f);
            short4 s4;
            s4.x = f2bf(xr[i].x); s4.y = f2bf(xr[i].y);
            s4.z = f2bf(xr[i].z); s4.w = f2bf(xr[i].w);
            *(short4*)(smem + sr * 256 + ((c4 * 2) ^ ((sr & 7) << 4))) = s4;
        }
    }
    __syncthreads();
    // ---- Q phase: diag (registers) ----
    float dg[4][4];
    {
        short8 Bq[8];
#pragma unroll
        for (int kk = 0; kk < 4; ++kk)
#pragma unroll
            for (int nc = 0; nc < 2; ++nc)
                Bq[kk * 2 + nc] = *(const short8*)&wqst[(w * 32 + nc * 16 + li) * 128 + kk * 32 + lg * 8];
#pragma unroll
        for (int mr = 0; mr < 4; ++mr) {
            f32x4 aq[2];
#pragma unroll
            for (int nc = 0; nc < 2; ++nc) aq[nc] = (f32x4){0.f,0.f,0.f,0.f};
#pragma unroll
            for (int kk = 0; kk < 4; ++kk) {
                const int row = mr * 16 + li;
                const short8 a = *(const short8*)(smem + row * 256 + (((kk * 32 + lg * 8) * 2) ^ ((row & 7) << 4)));
#pragma unroll
                for (int nc = 0; nc < 2; ++nc) aq[nc] = MFMA16(a, Bq[kk * 2 + nc], aq[nc]);
            }
#pragma unroll
            for (int r = 0; r < 4; ++r) {
                const float v0 = aq[0][r] + bq_r[0], v1 = aq[1][r] + bq_r[1];
                dg[mr][r] = 0.5f * bsum16(v0 * v0 + v1 * v1);
            }
        }
    }
    // ---- Kf hoist ----
    short8 Kf[4];
#pragma unroll
    for (int kk = 0; kk < 2; ++kk)
#pragma unroll
        for (int nc = 0; nc < 2; ++nc)
            Kf[kk * 2 + nc] = *(const short8*)&kvst[(w * 32 + nc * 16 + li) * 64 + kk * 32 + lg * 8];
    // ---- QD + softmax + Z per mr ----
#pragma unroll
    for (int mr = 0; mr < 4; ++mr) {
        f32x4 ad[4];
#pragma unroll
        for (int hf = 0; hf < 2; ++hf) {
            short8 Bf[8];
#pragma unroll
            for (int kk = 0; kk < 4; ++kk)
#pragma unroll
                for (int nc = 0; nc < 2; ++nc)
                    Bf[kk * 2 + nc] = *(const short8*)&w2qt[(w * 64 + (hf * 2 + nc) * 16 + li) * 128 + kk * 32 + lg * 8];
            f32x4 a0 = (f32x4){0.f,0.f,0.f,0.f}, a1 = (f32x4){0.f,0.f,0.f,0.f};
#pragma unroll
            for (int kk = 0; kk < 4; ++kk) {
                const int row = mr * 16 + li;
                const short8 a = *(const short8*)(smem + row * 256 + (((kk * 32 + lg * 8) * 2) ^ ((row & 7) << 4)));
                a0 = MFMA16(a, Bf[kk * 2 + 0], a0);
                a1 = MFMA16(a, Bf[kk * 2 + 1], a1);
            }
            ad[hf * 2 + 0] = a0; ad[hf * 2 + 1] = a1;
        }
        float zd[4];
#pragma unroll
        for (int r = 0; r < 4; ++r) {
            float vv[4];
#pragma unroll
            for (int nc = 0; nc < 4; ++nc) vv[nc] = ad[nc][r] + b2_r[nc];
            float mx = fmaxf(fmaxf(vv[0], vv[1]), fmaxf(vv[2], vv[3]));
            mx = bmax16(mx);
            const int rr = lg * 4 + r;
            float z = 0.f;
#pragma unroll
            for (int nc = 0; nc < 4; ++nc) {
                const float e = RATIO * (__expf(vv[nc] - dg[mr][r] - mx) + KEPS);
                z = fmaf(e, ksv[nc], z);
                const unsigned pe = (unsigned)(unsigned short)f2bf(e);
                const unsigned po = (unsigned)__shfl_xor((int)pe, 1);
                if (!(li & 1))
                    *(unsigned*)(qpb + rr * 128 +
                        ((nc * 32 + 2 * li) ^ ((rr & 7) << 4))) = pe | (po << 16);
            }
            zd[r] = bsum16(z);
        }
        f32x4 az[2];
#pragma unroll
        for (int nc = 0; nc < 2; ++nc) az[nc] = (f32x4){0.f,0.f,0.f,0.f};
#pragma unroll
        for (int kk = 0; kk < 2; ++kk) {
            const short8 aa = *(const short8*)(qpb + li * 128 +
                              ((kk * 64 + lg * 16) ^ ((li & 7) << 4)));
#pragma unroll
            for (int nc = 0; nc < 2; ++nc) az[nc] = MFMA16(aa, Kf[kk * 2 + nc], az[nc]);
        }
#pragma unroll
        for (int nc = 0; nc < 2; ++nc)
#pragma unroll
            for (int r = 0; r < 4; ++r) {
                const int row = mr * 16 + lg * 4 + r;
                const float zv = az[nc][r] / zd[r];
                const unsigned pe = (unsigned)(unsigned short)f2bf(zv);
                const unsigned po = (unsigned)__shfl_xor((int)pe, 1);
                if (!(li & 1))
                    *(unsigned*)(smem + 16384 + row * 512 +
                        ((2 * (w * 32 + nc * 16 + li)) ^ ((row & 7) << 4))) = pe | (po << 16);
            }
    }
    // ---- O weights issued before barrier ----
    short8 Bo[8];
#pragma unroll
    for (int kk = 0; kk < 8; ++kk)
        Bo[kk] = *(const short8*)&wot[(w * 16 + li) * 256 + kk * 32 + lg * 8];
    __syncthreads();   // zs complete
    f32x4 ao[4];
#pragma unroll
    for (int mr = 0; mr < 4; ++mr) ao[mr] = (f32x4){0.f,0.f,0.f,0.f};
#pragma unroll
    for (int mr = 0; mr < 4; ++mr)
#pragma unroll
        for (int kk = 0; kk < 8; ++kk) {
            const int row = mr * 16 + li;
            const short8 aa = *(const short8*)(smem + 16384 + row * 512 +
                              ((kk * 64 + lg * 16) ^ ((row & 7) << 4)));
            ao[mr] = MFMA16(aa, Bo[kk], ao[mr]);
        }
    __syncthreads();   // all zs reads done; region reusable as xn
    // ---- xn (= z@Wo + bo) -> LDS fp32 [64][132] ----
    float* xnb = (float*)(smem + 16384);
#pragma unroll
    for (int mr = 0; mr < 4; ++mr)
#pragma unroll
        for (int r = 0; r < 4; ++r) {
            const int row = mr * 16 + lg * 4 + r;
            xnb[row * 132 + w * 16 + li] = ao[mr][r] + bo;
        }
    __syncthreads();
    // ---- final: coalesced full-line float4 stores ----
    {
        const int c4 = (t & 31) * 4;
#pragma unroll
        for (int i = 0; i < 4; ++i) {
            const int sr = (t >> 5) + i * 16;
            const int n = n0 + sr;
            if (n < NN) {
                const float4 xn4 = *(const float4*)&xnb[sr * 132 + c4];
                float4 o4;
                o4.x = a2 * xr[i].x + bc * xn4.x;
                o4.y = a2 * xr[i].y + bc * xn4.y;
                o4.z = a2 * xr[i].z + bc * xn4.z;
                o4.w = a2 * xr[i].w + bc * xn4.w;
                *(float4*)(out + (size_t)n * 128 + c4) = o4;
            }
        }
    }
}

extern "C" void kernel_launch(void* const* d_in, const int* in_sizes, int n_in,
                              void* d_out, int out_size, void* d_ws, size_t ws_size,
                              hipStream_t stream) {
    (void)in_sizes; (void)n_in; (void)out_size;
    const float* x    = (const float*)d_in[0];
    const float* Wq_w = (const float*)d_in[2];
    const float* Wq_b = (const float*)d_in[3];
    const float* Wk_w = (const float*)d_in[4];
    const float* Wk_b = (const float*)d_in[5];
    const float* Wv_w = (const float*)d_in[6];
    const float* Wv_b = (const float*)d_in[7];
    const float* Wo_w = (const float*)d_in[8];
    const float* Wo_b = (const float*)d_in[9];
    const float* alpha= (const float*)d_in[10];
    const float* beta = (const float*)d_in[11];
    const float* proj = (const float*)d_in[12];
    float* out = (float*)d_out;
    float* ws  = (float*)d_ws;

    float* kmax     = ws + WS_KMAX;
    float* red2     = ws + WS_RED2;
    float* partials = ws + WS_PART;
    const size_t availf = (ws_size / 4 > (size_t)WS_PART) ? (ws_size / 4 - WS_PART) : 0;
    int nb = (int)(availf / 16896);
    if (nb > 625) nb = 625;
    if (nb < 1) nb = 1;

    init_kernel<<<1, 64, 0, stream>>>(kmax);
    fold_kernel<<<258, 256, 0, stream>>>(Wq_w, Wq_b, proj, ws + WS_W2Q, ws + WS_B2Q);
    fold_kernel<<<258, 256, 0, stream>>>(Wk_w, Wk_b, proj, ws + WS_W2K, ws + WS_B2K);
    prep_kernel<<<1027, 256, 0, stream>>>(Wq_w, Wq_b, Wk_w, Wk_b, Wv_w, Wv_b, Wo_w, ws);
    kmax_mfma_kernel<<<1563, 512, 0, stream>>>(x, ws, kmax);
    kvs_mfma_kernel<<<nb, 512, 0, stream>>>(x, ws, partials, nb);
    reduce1_kernel<<<528, 256, 0, stream>>>(partials, red2, nb);
    reduce2_kernel<<<66, 256, 0, stream>>>(red2, ws);
    out_mfma_kernel<<<1563, 512, 0, stream>>>(x, ws, alpha, beta, Wo_b, out);
}